// Round 16
// baseline (183.122 us; speedup 1.0000x reference)
//
#include <hip/hip_runtime.h>
#include <cstdint>
#include <cstddef>

typedef unsigned short ushort_t;
typedef unsigned int uint_t;
typedef __attribute__((ext_vector_type(8))) short bf16x8;
typedef __attribute__((ext_vector_type(4))) float f32x4;

#define NB 128
#define NC 128
#define NL 256
#define NH 8
#define HD 16
#define HDV 64
#define NEV 512
#define PHALF 4194304   // elements per conv1 partial half (128*256*128)

__device__ __forceinline__ ushort_t f2bf(float f) {
    uint_t u = __float_as_uint(f);
    u += 0x7fffu + ((u >> 16) & 1u);
    return (ushort_t)(u >> 16);
}
__device__ __forceinline__ float bf2f(ushort_t s) {
    return __uint_as_float(((uint_t)s) << 16);
}
// single-instruction packed f32->bf16 (RNE), lo in low 16 bits
__device__ __forceinline__ uint_t pack2(float lo, float hi) {
    uint_t r;
    asm("v_cvt_pk_bf16_f32 %0, %1, %2" : "=v"(r) : "v"(lo), "v"(hi));
    return r;
}

// ---------------- K0: pack conv weights, GRP frags per-lane contiguous.
template<int CIN, int GRP>
__global__ __launch_bounds__(256) void k_wpack(const float* __restrict__ w,
                                               short* __restrict__ wp) {
    int idx = blockIdx.x * 256 + threadIdx.x;
    if (idx >= CIN * 1152) return;      // CIN*9*128 elements
    constexpr int LG = (GRP == 4) ? 2 : 1;
    int j    = idx & 7;
    int r    = (idx >> 3) & (GRP - 1);
    int lane = (idx >> (3 + LG)) & 63;
    int gidx = (idx >> (9 + LG)) & ((8 / GRP) - 1);
    int tc   = idx >> 12;
    int tap  = tc % 9;
    int ch   = tc / 9;
    int co   = (gidx * GRP + r) * 16 + (lane & 15);
    int ci   = ch * 32 + (lane >> 4) * 8 + j;
    wp[idx] = (short)f2bf(w[((size_t)co * CIN + ci) * 9 + tap]);
}

// ---------------- K0b: pack projection weights (E x 128) into A-frag order
template<int E>
__global__ __launch_bounds__(256) void k_wpack_qkv(const float* __restrict__ w,
                                                   short* __restrict__ wp) {
    int idx = blockIdx.x * 256 + threadIdx.x;
    if (idx >= E * 128) return;
    int j    = idx & 7;
    int lane = (idx >> 3) & 63;
    int ch   = (idx >> 9) & 3;
    int rt   = idx >> 11;
    int n = lane & 15, g = lane >> 4;
    wp[idx] = (short)f2bf(w[(size_t)(rt*16 + n)*128 + ch*32 + g*8 + j]);
}

// ---------------- K0c: transpose X (NCHW f32) -> xbf (NHWC bf16), once.
__global__ __launch_bounds__(256) void k_xpose(const float* __restrict__ x,
                                               ushort_t* __restrict__ xbf) {
    const int half = blockIdx.x, b = blockIdx.y, t = threadIdx.x;
    const float* src = x + (size_t)b*NC*NL + (size_t)half*64*NL + t;
    uint_t* dst = (uint_t*)(xbf + ((size_t)b*NL + t)*NC + half*64);
    #pragma unroll
    for (int k8 = 0; k8 < 8; ++k8) {
        uint4 u;
        u.x = pack2(src[(k8*8+0)*NL], src[(k8*8+1)*NL]);
        u.y = pack2(src[(k8*8+2)*NL], src[(k8*8+3)*NL]);
        u.z = pack2(src[(k8*8+4)*NL], src[(k8*8+5)*NL]);
        u.w = pack2(src[(k8*8+6)*NL], src[(k8*8+7)*NL]);
        *(uint4*)(dst + k8*4) = u;
    }
}

// ---------------- K1: full-MFMA position attention. Block = (h, b), 8 waves x 32 q.
__global__ __launch_bounds__(512, 4) void k_pos_mfma(
    const ushort_t* __restrict__ xbf,
    const short* __restrict__ wpq, const short* __restrict__ wpk,
    const short* __restrict__ wpv,
    const float* __restrict__ bq, const float* __restrict__ bk,
    const float* __restrict__ bv,
    ushort_t* __restrict__ att)
{
    const int h = blockIdx.x, b = blockIdx.y;
    const int t = threadIdx.x;
    const int lane = t & 63, w = t >> 6;
    const int n = lane & 15, g = lane >> 4;

    __shared__ __align__(16) short lds[26112];   // 52,224 B

    const f32x4 z4 = {0.f, 0.f, 0.f, 0.f};
    f32x4 qacc[2], kacc[2], vacc[4][2];
    #pragma unroll
    for (int ct = 0; ct < 2; ++ct) { qacc[ct] = z4; kacc[ct] = z4; }
    #pragma unroll
    for (int vt = 0; vt < 4; ++vt)
        #pragma unroll
        for (int ct = 0; ct < 2; ++ct) vacc[vt][ct] = z4;

    const ushort_t* xr = xbf + ((size_t)(b*NL + w*32 + n))*NC;

    #pragma unroll 2
    for (int ch = 0; ch < 4; ++ch) {
        bf16x8 xb[2];
        #pragma unroll
        for (int ct = 0; ct < 2; ++ct)
            xb[ct] = *(const bf16x8*)(xr + ct*16*NC + ch*32 + g*8);
        const size_t fo = ((size_t)((h*4 + ch)*64) + lane) * 8;
        {
            bf16x8 aq = *(const bf16x8*)(wpq + fo);
            #pragma unroll
            for (int ct = 0; ct < 2; ++ct)
                qacc[ct] = __builtin_amdgcn_mfma_f32_16x16x32_bf16(aq, xb[ct], qacc[ct], 0, 0, 0);
        }
        {
            bf16x8 ak = *(const bf16x8*)(wpk + fo);
            #pragma unroll
            for (int ct = 0; ct < 2; ++ct)
                kacc[ct] = __builtin_amdgcn_mfma_f32_16x16x32_bf16(ak, xb[ct], kacc[ct], 0, 0, 0);
        }
        #pragma unroll
        for (int vt = 0; vt < 4; ++vt) {
            bf16x8 av = *(const bf16x8*)(wpv + ((size_t)((((h*4 + vt)*4) + ch)*64) + lane) * 8);
            #pragma unroll
            for (int ct = 0; ct < 2; ++ct)   // SWAPPED: D[l][dv]
                vacc[vt][ct] = __builtin_amdgcn_mfma_f32_16x16x32_bf16(xb[ct], av, vacc[vt][ct], 0, 0, 0);
        }
    }

    uint_t qu01[2], qu23[2];
    {
        float bqv[4], bkv[4];
        #pragma unroll
        for (int r = 0; r < 4; ++r) {
            bqv[r] = bq[h*16 + g*4 + r];
            bkv[r] = bk[h*16 + g*4 + r];
        }
        #pragma unroll
        for (int ct = 0; ct < 2; ++ct) {
            qu01[ct] = pack2(qacc[ct][0] + bqv[0], qacc[ct][1] + bqv[1]);
            qu23[ct] = pack2(qacc[ct][2] + bqv[2], qacc[ct][3] + bqv[3]);
            uint2 kp;
            kp.x = pack2(kacc[ct][0] + bkv[0], kacc[ct][1] + bkv[1]);
            kp.y = pack2(kacc[ct][2] + bkv[2], kacc[ct][3] + bkv[3]);
            *(uint2*)&lds[(w*32 + ct*16 + n)*16 + g*4] = kp;
        }
        #pragma unroll
        for (int vt = 0; vt < 4; ++vt) {
            const float bvv = bv[h*64 + vt*16 + n];
            #pragma unroll
            for (int ct = 0; ct < 2; ++ct) {
                uint2 vp;
                vp.x = pack2(vacc[vt][ct][0] + bvv, vacc[vt][ct][1] + bvv);
                vp.y = pack2(vacc[vt][ct][2] + bvv, vacc[vt][ct][3] + bvv);
                *(uint2*)&lds[9216 + (vt*16 + n)*264 + w*32 + ct*16 + g*4] = vp;
            }
        }
    }
    __syncthreads();

    const int a0 = (n + 32*(g & 1)) * 4;
    #pragma unroll 1
    for (int qt = 0; qt < 2; ++qt) {
        union { uint_t u[4]; bf16x8 v; } qfu;
        qfu.u[0] = (uint_t)__builtin_amdgcn_ds_bpermute(a0,      (int)qu01[qt]);
        qfu.u[1] = (uint_t)__builtin_amdgcn_ds_bpermute(a0,      (int)qu23[qt]);
        qfu.u[2] = (uint_t)__builtin_amdgcn_ds_bpermute(a0 + 64, (int)qu01[qt]);
        qfu.u[3] = (uint_t)__builtin_amdgcn_ds_bpermute(a0 + 64, (int)qu23[qt]);
        if (g >= 2) { qfu.u[0] = 0; qfu.u[1] = 0; qfu.u[2] = 0; qfu.u[3] = 0; }
        bf16x8 qf = qfu.v;

        f32x4 s[16];
        #pragma unroll
        for (int kt = 0; kt < 16; ++kt) {
            bf16x8 kf = (bf16x8){0,0,0,0,0,0,0,0};
            if (g < 2) kf = *(const bf16x8*)&lds[(kt*16 + n)*16 + g*8];
            s[kt] = __builtin_amdgcn_mfma_f32_16x16x32_bf16(kf, qf, z4, 0, 0, 0);
        }
        float d0 = 0.f, d1 = 0.f, d2 = 0.f, d3 = 0.f;
        #pragma unroll
        for (int kt = 0; kt < 16; ++kt) {
            float e0 = exp2f(s[kt][0] * 0.36067376022224085f);
            float e1 = exp2f(s[kt][1] * 0.36067376022224085f);
            float e2 = exp2f(s[kt][2] * 0.36067376022224085f);
            float e3 = exp2f(s[kt][3] * 0.36067376022224085f);
            s[kt][0] = e0; s[kt][1] = e1; s[kt][2] = e2; s[kt][3] = e3;
            d0 += e0; d1 += e1; d2 += e2; d3 += e3;
        }
        float den = (d0 + d1) + (d2 + d3);
        den += __shfl_xor(den, 16);
        den += __shfl_xor(den, 32);
        const float inv = 1.f / den;

        f32x4 oacc[4] = {z4, z4, z4, z4};
        #pragma unroll
        for (int c2 = 0; c2 < 8; ++c2) {
            #pragma unroll
            for (int u = 0; u < 2; ++u) {
                const int kt = 2*c2 + u;
                uint2 pp;
                pp.x = pack2(s[kt][0], s[kt][1]);
                pp.y = pack2(s[kt][2], s[kt][3]);
                *(uint2*)&lds[4096 + w*640 + n*40 + u*16 + g*4] = pp;
            }
            bf16x8 pf = *(const bf16x8*)&lds[4096 + w*640 + n*40 + g*8];
            #pragma unroll
            for (int vt = 0; vt < 4; ++vt) {
                bf16x8 av = *(const bf16x8*)&lds[9216 + (vt*16 + n)*264 + c2*32 + g*8];
                oacc[vt] = __builtin_amdgcn_mfma_f32_16x16x32_bf16(av, pf, oacc[vt], 0, 0, 0);
            }
        }
        ushort_t* ap = att + (((size_t)b*NL + (w*32 + qt*16 + n))*NEV + h*HDV + g*4);
        #pragma unroll
        for (int vt = 0; vt < 4; ++vt) {
            uint2 op;
            op.x = pack2(oacc[vt][0]*inv, oacc[vt][1]*inv);
            op.y = pack2(oacc[vt][2]*inv, oacc[vt][3]*inv);
            *(uint2*)(ap + vt*16) = op;
        }
    }
}

// ---------------- K2: conv1 (3x3, 512->128), A-reuse-8 implicit GEMM.
// grid (4, NB): blockIdx.x = kc*2 + lh. Block = 128co x 128l x 256ci.
// 4 waves = (2 co-halves x 2 ci-halves); wave tile 64co x 128l x 128ci, acc 4x8.
// LDS: per ci-half 10-row haloed image, double-buffered: 2x2x5760 shorts = 46 KB.
// Epilogue: upper-ci waves pass acc (bf16) via LDS; lower waves fold + emit P.
__global__ __launch_bounds__(256, 2) void k_conv_ci(
    const ushort_t* __restrict__ att, const short* __restrict__ wp,
    ushort_t* __restrict__ P)
{
    const int kc = blockIdx.x >> 1, lh = blockIdx.x & 1, b = blockIdx.y;
    const int t = threadIdx.x;
    const int lane = t & 63, w = t >> 6;
    const int wci = w >> 1, wr = w & 1;          // ci-half, co-half
    const int n = lane & 15, gl = lane >> 4;
    const int y0 = lh * 8;

    __shared__ __align__(16) short ims[23040];   // 2 ci-halves x 2 dbuf x 5760

    {   // zero everything once (x halo cols 0/17 stay zero; oob rows re-zeroed per chunk)
        bf16x8 z = {0,0,0,0,0,0,0,0};
        bf16x8* p = (bf16x8*)ims;
        for (int i = t; i < 2880; i += 256) p[i] = z;
    }

    f32x4 acc[4][8];
    #pragma unroll
    for (int i = 0; i < 4; ++i)
        #pragma unroll
        for (int j = 0; j < 8; ++j) acc[i][j] = (f32x4){0.f,0.f,0.f,0.f};

    // staging: 1280 tasks = 2 halves x 10 yp x 16 xx x 4 gg; 5 per thread
    const ushort_t* abase = att + (size_t)b*NL*NEV + kc*256;
    int soff[5], slotb[5];
    bool ok[5];
    #pragma unroll
    for (int i = 0; i < 5; ++i) {
        int id = t + 256*i;
        int half = (id >= 640) ? 1 : 0;
        int rem = id - half*640;
        int gg = rem & 3, xx = (rem >> 2) & 15, yp = rem >> 6;   // yp 0..9
        int y = y0 - 1 + yp;
        ok[i] = (y >= 0) && (y < 16);
        soff[i]  = (y*16 + xx)*NEV + half*128 + gg*8;
        slotb[i] = half*11520 + ((yp*4 + gg)*18 + xx + 1)*8;
    }
    bf16x8 pre[5];
    #pragma unroll
    for (int i = 0; i < 5; ++i) {
        pre[i] = (bf16x8){0,0,0,0,0,0,0,0};
        if (ok[i]) pre[i] = *(const bf16x8*)(abase + soff[i]);
    }

    const short* wpl = wp + (size_t)lane * 32;

    __syncthreads();      // zero-init done

    #pragma unroll 1
    for (int ch = 0; ch < 4; ++ch) {
        const int ch16 = kc*8 + wci*4 + ch;
        const int boff = (ch & 1) * 5760;
        #pragma unroll
        for (int i = 0; i < 5; ++i)
            *(bf16x8*)&ims[slotb[i] + boff] = pre[i];
        __syncthreads();
        if (ch < 3) {                  // T14: issue next chunk after barrier
            #pragma unroll
            for (int i = 0; i < 5; ++i)
                if (ok[i]) pre[i] = *(const bf16x8*)(abase + soff[i] + (ch + 1)*32);
        }
        const short* imb = &ims[wci*11520 + boff];
        #pragma unroll
        for (int tap = 0; tap < 9; ++tap) {
            const int dy = tap / 3, dx = tap % 3;
            const bf16x8* ap = (const bf16x8*)(wpl +
                ((size_t)((ch16*9 + tap)*2 + wr)) * 2048);
            bf16x8 A0 = ap[0], A1 = ap[1], A2 = ap[2], A3 = ap[3];
            bf16x8 Bf[8];
            #pragma unroll
            for (int ct = 0; ct < 8; ++ct)
                Bf[ct] = *(const bf16x8*)&imb[(((ct + dy)*4 + gl)*18 + n + dx) * 8];
            #pragma unroll
            for (int ct = 0; ct < 8; ++ct) {
                acc[0][ct] = __builtin_amdgcn_mfma_f32_16x16x32_bf16(A0, Bf[ct], acc[0][ct], 0, 0, 0);
                acc[1][ct] = __builtin_amdgcn_mfma_f32_16x16x32_bf16(A1, Bf[ct], acc[1][ct], 0, 0, 0);
                acc[2][ct] = __builtin_amdgcn_mfma_f32_16x16x32_bf16(A2, Bf[ct], acc[2][ct], 0, 0, 0);
                acc[3][ct] = __builtin_amdgcn_mfma_f32_16x16x32_bf16(A3, Bf[ct], acc[3][ct], 0, 0, 0);
            }
        }
        __syncthreads();               // compute done before buffer reuse (2 chunks later)
    }

    // ---- combine ci-halves via LDS (bf16), lower waves emit P
    uint_t* red = (uint_t*)ims;        // 2 wr x 4 rt x 8 ct x 64 lanes x 2 uint = 32 KB
    if (wci == 1) {
        #pragma unroll
        for (int rt = 0; rt < 4; ++rt)
            #pragma unroll
            for (int ct = 0; ct < 8; ++ct) {
                const int o = ((((wr*4 + rt)*8 + ct)*64 + lane)) * 2;
                red[o]     = pack2(acc[rt][ct][0], acc[rt][ct][1]);
                red[o + 1] = pack2(acc[rt][ct][2], acc[rt][ct][3]);
            }
    }
    __syncthreads();
    if (wci == 0) {
        ushort_t* Pb = P + (size_t)kc * PHALF + (size_t)b * NL * NC;
        #pragma unroll
        for (int rt = 0; rt < 4; ++rt) {
            const int co0 = wr*64 + rt*16 + gl*4;
            #pragma unroll
            for (int ct = 0; ct < 8; ++ct) {
                const int o = ((((wr*4 + rt)*8 + ct)*64 + lane)) * 2;
                const uint_t u0 = red[o], u1 = red[o + 1];
                const float a0 = acc[rt][ct][0] + bf2f((ushort_t)(u0 & 0xffffu));
                const float a1 = acc[rt][ct][1] + bf2f((ushort_t)(u0 >> 16));
                const float a2 = acc[rt][ct][2] + bf2f((ushort_t)(u1 & 0xffffu));
                const float a3 = acc[rt][ct][3] + bf2f((ushort_t)(u1 >> 16));
                const int l = lh*128 + ct*16 + n;
                uint2 u;
                u.x = pack2(a0, a1);
                u.y = pack2(a2, a3);
                *(uint2*)(Pb + (size_t)l*NC + co0) = u;
            }
        }
    }
}

// ---------------- K4: conv2 (3x3, 128->128) co+l-split, T14 + depth-3 A pipeline.
__global__ __launch_bounds__(256, 2) void k_conv_co(
    const ushort_t* __restrict__ comb, const short* __restrict__ wp,
    const float* __restrict__ bias, float* __restrict__ out)
{
    const int kc = blockIdx.x >> 1, lh = blockIdx.x & 1, b = blockIdx.y;
    const int t = threadIdx.x;
    const int lane = t & 63, w = t >> 6;
    const int wr = w >> 1, wc = w & 1;
    const int n = lane & 15, gl = lane >> 4;
    const int y0 = lh * 8;

    __shared__ __align__(16) short ims[2][5760];

    {
        bf16x8 z = {0,0,0,0,0,0,0,0};
        bf16x8* p = (bf16x8*)&ims[0][0];
        for (int i = t; i < 1440; i += 256) p[i] = z;
    }

    f32x4 acc[2][4];
    #pragma unroll
    for (int i = 0; i < 2; ++i)
        #pragma unroll
        for (int j = 0; j < 4; ++j) acc[i][j] = (f32x4){0.f,0.f,0.f,0.f};

    const int gg1 = t & 3,        xx1 = (t >> 2) & 15,        yp1 = t >> 6;
    const int id2 = t + 256;
    const int gg2 = id2 & 3,      xx2 = (id2 >> 2) & 15,      yp2 = id2 >> 6;
    const int id3 = t + 512;
    const int gg3 = id3 & 3,      xx3 = (id3 >> 2) & 15,      yp3 = id3 >> 6;
    const bool has3 = (t < 128);
    const int y1 = y0 - 1 + yp1, y2 = y0 - 1 + yp2, y3 = y0 - 1 + yp3;
    const bool ok1 = (y1 >= 0) && (y1 < 16);
    const bool ok2 = (y2 >= 0) && (y2 < 16);
    const bool ok3 = has3 && (y3 >= 0) && (y3 < 16);
    const ushort_t* s1 = comb + ((size_t)(b*NL + y1*16 + xx1))*NC + gg1*8;
    const ushort_t* s2 = comb + ((size_t)(b*NL + y2*16 + xx2))*NC + gg2*8;
    const ushort_t* s3 = comb + ((size_t)(b*NL + y3*16 + xx3))*NC + gg3*8;
    const int slot1 = ((yp1*4 + gg1)*18 + xx1 + 1) * 8;
    const int slot2 = ((yp2*4 + gg2)*18 + xx2 + 1) * 8;
    const int slot3 = ((yp3*4 + gg3)*18 + xx3 + 1) * 8;

    bf16x8 v1 = {0,0,0,0,0,0,0,0}, v2 = v1, v3 = v1;
    if (ok1) v1 = *(const bf16x8*)s1;
    if (ok2) v2 = *(const bf16x8*)s2;
    if (ok3) v3 = *(const bf16x8*)s3;

    const short* wpl = wp + (size_t)lane * 16;
    auto Aaddr = [&](int ch, int tap) {
        return (const bf16x8*)(wpl + ((size_t)((ch*9 + tap)*4 + kc*2 + wr)) * 1024);
    };

    bf16x8 Abuf[3][2];
    bf16x8 Bc[4], Bn[4];
    #pragma unroll
    for (int i = 0; i < 4; ++i) { Bc[i] = (bf16x8){0,0,0,0,0,0,0,0}; Bn[i] = Bc[i]; }

    __syncthreads();

    #pragma unroll 1
    for (int ch = 0; ch < 4; ++ch) {
        short* buf = &ims[ch & 1][0];
        *(bf16x8*)&buf[slot1] = v1;
        *(bf16x8*)&buf[slot2] = v2;
        if (has3) *(bf16x8*)&buf[slot3] = v3;
        __syncthreads();
        if (ch < 3) {                        // T14: issue after barrier
            if (ok1) v1 = *(const bf16x8*)(s1 + (ch + 1) * 32);
            if (ok2) v2 = *(const bf16x8*)(s2 + (ch + 1) * 32);
            if (ok3) v3 = *(const bf16x8*)(s3 + (ch + 1) * 32);
        }
        #pragma unroll
        for (int p = 0; p < 3; ++p) {
            const bf16x8* ap = Aaddr(ch, p);
            #pragma unroll
            for (int rt = 0; rt < 2; ++rt) Abuf[p][rt] = ap[rt];
        }
        #pragma unroll
        for (int ct = 0; ct < 4; ++ct)
            Bc[ct] = *(const bf16x8*)&buf[(((wc*4 + ct)*4 + gl)*18 + n) * 8];

        #pragma unroll
        for (int tap = 0; tap < 9; ++tap) {
            if (tap < 8) {
                const int dy = (tap + 1) / 3, dx = (tap + 1) % 3;
                #pragma unroll
                for (int ct = 0; ct < 4; ++ct)
                    Bn[ct] = *(const bf16x8*)&buf[(((wc*4 + ct + dy)*4 + gl)*18 + n + dx) * 8];
            }
            #pragma unroll
            for (int rt = 0; rt < 2; ++rt)
                #pragma unroll
                for (int ct = 0; ct < 4; ++ct)
                    acc[rt][ct] = __builtin_amdgcn_mfma_f32_16x16x32_bf16(
                        Abuf[tap % 3][rt], Bc[ct], acc[rt][ct], 0, 0, 0);
            if (tap + 3 < 9) {
                const bf16x8* ap = Aaddr(ch, tap + 3);
                #pragma unroll
                for (int rt = 0; rt < 2; ++rt) Abuf[tap % 3][rt] = ap[rt];
            }
            #pragma unroll
            for (int i = 0; i < 4; ++i)
                if (tap < 8) Bc[i] = Bn[i];
        }
    }

    #pragma unroll
    for (int rt = 0; rt < 2; ++rt) {
        const int co0 = kc*64 + wr*32 + rt*16 + gl*4;
        const float c0 = bias[co0+0], c1 = bias[co0+1],
                    c2 = bias[co0+2], c3 = bias[co0+3];
        #pragma unroll
        for (int ct = 0; ct < 4; ++ct) {
            const int l = lh*128 + wc*64 + ct*16 + n;
            f32x4 a = acc[rt][ct];
            out[((size_t)b*NC + co0+0)*NL + l] = c0 + a[0];
            out[((size_t)b*NC + co0+1)*NL + l] = c1 + a[1];
            out[((size_t)b*NC + co0+2)*NL + l] = c2 + a[2];
            out[((size_t)b*NC + co0+3)*NL + l] = c3 + a[3];
        }
    }
}

// ---------------- K3: channel attention + fold conv1 partials + pos residual + fusion.
#define NLP 260
__global__ __launch_bounds__(256) void k_cha(
    const float* __restrict__ xc,
    const float* __restrict__ cwq, const float* __restrict__ cbq,
    const float* __restrict__ cwk, const float* __restrict__ cbk,
    const float* __restrict__ cwv, const float* __restrict__ cbv,
    const float* __restrict__ cwo, const float* __restrict__ cbo,
    const float* __restrict__ gamma,
    const ushort_t* __restrict__ P, const float* __restrict__ qpos,
    const float* __restrict__ pbo, const float* __restrict__ gpos,
    ushort_t* __restrict__ comb)
{
    const int h = blockIdx.x, b = blockIdx.y, t = threadIdx.x;
    __shared__ float qh[16][NLP];
    __shared__ float G_s[16][17];
    __shared__ float S_s[16];
    __shared__ float wq_s[128], bq_s[128], wk_s[128], bk_s[128], wv_s[128], bv_s[128];
    __shared__ float A_s[128][17];
    __shared__ float B_s[128];
    __shared__ float M_s[16][17];
    __shared__ float c_s[16];

    #pragma unroll
    for (int j = 0; j < 16; ++j)
        qh[j][t] = xc[((size_t)b*NC + h*16 + j)*NL + t];
    if (t < 128) {
        const int k = h*128 + t;
        wq_s[t] = cwq[k]; bq_s[t] = cbq[k];
        wk_s[t] = cwk[k]; bk_s[t] = cbk[k];
        wv_s[t] = cwv[k]; bv_s[t] = cbv[k];
    }
    __syncthreads();
    {
        const int i = t >> 4, j = t & 15;
        const float4* qi = (const float4*)qh[i];
        const float4* qj = (const float4*)qh[j];
        float gg = 0.f;
        for (int l4 = 0; l4 < NL/4; ++l4) {
            float4 a = qi[l4], c = qj[l4];
            gg = fmaf(a.x,c.x,fmaf(a.y,c.y,fmaf(a.z,c.z,fmaf(a.w,c.w,gg))));
        }
        G_s[i][j] = gg;
    }
    if (t < 16) {
        const float4* qi = (const float4*)qh[t];
        float s = 0.f;
        for (int l4 = 0; l4 < NL/4; ++l4) { float4 a = qi[l4]; s += a.x + a.y + a.z + a.w; }
        S_s[t] = s;
    }
    __syncthreads();
    if (t < 128) {
        const int c2 = t, cg = c2 >> 3;
        const float wqc = wq_s[c2], bqc = bq_s[c2];
        float Pv[16];
        #pragma unroll
        for (int j = 0; j < 16; ++j) Pv[j] = wqc*G_s[cg][j] + bqc*S_s[j];
        const float Qc = wqc*S_s[cg] + bqc*256.0f;
        float mx = -3.0e38f;
        #pragma unroll
        for (int dg = 0; dg < 16; ++dg) {
            #pragma unroll
            for (int dj = 0; dj < 8; ++dj) {
                const int d = dg*8 + dj;
                float s = wk_s[d]*Pv[dg] + bk_s[d]*Qc;
                mx = fmaxf(mx, s);
            }
        }
        float A[16];
        #pragma unroll
        for (int j = 0; j < 16; ++j) A[j] = 0.f;
        float Bv = 0.f, den = 0.f;
        #pragma unroll
        for (int dg = 0; dg < 16; ++dg) {
            #pragma unroll
            for (int dj = 0; dj < 8; ++dj) {
                const int d = dg*8 + dj;
                float s = wk_s[d]*Pv[dg] + bk_s[d]*Qc;
                float e = __expf((s - mx) * 0.0625f);
                den += e;
                A[dg] = fmaf(e, wv_s[d], A[dg]);
                Bv = fmaf(e, bv_s[d], Bv);
            }
        }
        const float inv = 1.f / den;
        #pragma unroll
        for (int j = 0; j < 16; ++j) A_s[c2][j] = A[j]*inv;
        B_s[c2] = Bv*inv;
    }
    __syncthreads();
    {
        const int cl = t >> 4, j = t & 15;
        const int cp = h*16 + cl;
        float m = 0.f;
        #pragma unroll
        for (int hp = 0; hp < 8; ++hp)
            m = fmaf(cwo[cp*8+hp], A_s[cl*8+hp][j], m);
        M_s[cl][j] = m;
        if (j == 0) {
            float cc = cbo[cp];
            #pragma unroll
            for (int hp = 0; hp < 8; ++hp)
                cc = fmaf(cwo[cp*8+hp], B_s[cl*8+hp], cc);
            c_s[cl] = cc;
        }
    }
    __syncthreads();
    {
        const float g  = gamma[0];
        const float gp = gpos[0];
        const int l = t;
        float cv[16];
        #pragma unroll
        for (int cl = 0; cl < 16; ++cl) {
            float a = c_s[cl];
            #pragma unroll
            for (int j = 0; j < 16; ++j)
                a = fmaf(M_s[cl][j], qh[j][l], a);
            cv[cl] = a;
        }
        const ushort_t* p0 = P + ((size_t)b*NL + l)*NC + h*16;
        const ushort_t* p1 = p0 + PHALF;
        const float* qp = qpos + ((size_t)b*NC + h*16)*NL + l;
        #pragma unroll
        for (int q = 0; q < 4; ++q) {
            uint2 u0 = *(const uint2*)(p0 + 4*q);
            uint2 u1 = *(const uint2*)(p1 + 4*q);
            float s0 = bf2f((ushort_t)(u0.x & 0xffffu)) + bf2f((ushort_t)(u1.x & 0xffffu));
            float s1 = bf2f((ushort_t)(u0.x >> 16))     + bf2f((ushort_t)(u1.x >> 16));
            float s2 = bf2f((ushort_t)(u0.y & 0xffffu)) + bf2f((ushort_t)(u1.y & 0xffffu));
            float s3 = bf2f((ushort_t)(u0.y >> 16))     + bf2f((ushort_t)(u1.y >> 16));
            cv[4*q+0] = 0.5f*(qp[(4*q+0)*NL] + gp*(pbo[h*16+4*q+0] + s0) + qh[4*q+0][l] + g*cv[4*q+0]);
            cv[4*q+1] = 0.5f*(qp[(4*q+1)*NL] + gp*(pbo[h*16+4*q+1] + s1) + qh[4*q+1][l] + g*cv[4*q+1]);
            cv[4*q+2] = 0.5f*(qp[(4*q+2)*NL] + gp*(pbo[h*16+4*q+2] + s2) + qh[4*q+2][l] + g*cv[4*q+2]);
            cv[4*q+3] = 0.5f*(qp[(4*q+3)*NL] + gp*(pbo[h*16+4*q+3] + s3) + qh[4*q+3][l] + g*cv[4*q+3]);
        }
        ushort_t* cp = comb + ((size_t)b*NL + l)*NC + h*16;
        uint4 o0, o1;
        o0.x = pack2(cv[0],  cv[1]);   o0.y = pack2(cv[2],  cv[3]);
        o0.z = pack2(cv[4],  cv[5]);   o0.w = pack2(cv[6],  cv[7]);
        o1.x = pack2(cv[8],  cv[9]);   o1.y = pack2(cv[10], cv[11]);
        o1.z = pack2(cv[12], cv[13]);  o1.w = pack2(cv[14], cv[15]);
        *(uint4*)cp       = o0;
        *(uint4*)(cp + 8) = o1;
    }
}

extern "C" void kernel_launch(void* const* d_in, const int* in_sizes, int n_in,
                              void* d_out, int out_size, void* d_ws, size_t ws_size,
                              hipStream_t stream)
{
    const float* qpos = (const float*)d_in[0];
    const float* qcha = (const float*)d_in[1];
    const float* pwq  = (const float*)d_in[2];
    const float* pbq  = (const float*)d_in[3];
    const float* pwk  = (const float*)d_in[4];
    const float* pbk  = (const float*)d_in[5];
    const float* pwv  = (const float*)d_in[6];
    const float* pbv  = (const float*)d_in[7];
    const float* pwo  = (const float*)d_in[8];
    const float* pbo  = (const float*)d_in[9];
    const float* gpos = (const float*)d_in[10];
    const float* cwq  = (const float*)d_in[11];
    const float* cbq  = (const float*)d_in[12];
    const float* cwk  = (const float*)d_in[13];
    const float* cbk  = (const float*)d_in[14];
    const float* cwv  = (const float*)d_in[15];
    const float* cbv  = (const float*)d_in[16];
    const float* cwo  = (const float*)d_in[17];
    const float* cbo  = (const float*)d_in[18];
    const float* gcha = (const float*)d_in[19];
    const float* fw   = (const float*)d_in[20];
    const float* fb   = (const float*)d_in[21];
    float* outp = (float*)d_out;

    char* ws = (char*)d_ws;
    ushort_t* att  = (ushort_t*)ws;                       // 33,554,432 B (NHWC bf16)
    ushort_t* comb = (ushort_t*)ws;                       //  8,388,608 B (bf16 NHWC, overlays att)
    ushort_t* P    = (ushort_t*)(ws + 33554432);          // 16,777,216 B (2 bf16 partial halves)
    ushort_t* xbf  = (ushort_t*)(ws + 33554432);          //  8,388,608 B (overlays P; dead before conv_ci)
    short*    wp1  = (short*)(ws + 50331648);             //  1,179,648 B
    short*    wp2  = (short*)(ws + 51511296);             //    294,912 B
    short*    wpq  = (short*)(ws + 51806208);             //     32,768 B
    short*    wpk  = (short*)(ws + 51838976);             //     32,768 B
    short*    wpv  = (short*)(ws + 51871744);             //    131,072 B

    k_wpack<NEV, 4><<<dim3((NEV*1152 + 255)/256), 256, 0, stream>>>(pwo, wp1);
    k_wpack<NC,  2><<<dim3((NC *1152 + 255)/256), 256, 0, stream>>>(fw,  wp2);
    k_wpack_qkv<128><<<dim3(64),  256, 0, stream>>>(pwq, wpq);
    k_wpack_qkv<128><<<dim3(64),  256, 0, stream>>>(pwk, wpk);
    k_wpack_qkv<512><<<dim3(256), 256, 0, stream>>>(pwv, wpv);

    k_xpose<<<dim3(2, NB), 256, 0, stream>>>(qpos, xbf);
    k_pos_mfma<<<dim3(NH, NB), 512, 0, stream>>>(xbf, wpq, wpk, wpv,
                                                 pbq, pbk, pbv, att);
    k_conv_ci<<<dim3(4, NB), 256, 0, stream>>>(att, wp1, P);
    k_cha<<<dim3(NH, NB), 256, 0, stream>>>(qcha, cwq, cbq, cwk, cbk, cwv, cbv,
                                            cwo, cbo, gcha,
                                            P, qpos, pbo, gpos, comb);
    k_conv_co<<<dim3(4, NB), 256, 0, stream>>>(comb, wp2, fb, outp);
}

// Round 17
// 162.347 us; speedup vs baseline: 1.1280x; 1.1280x over previous
//
#include <hip/hip_runtime.h>
#include <cstdint>
#include <cstddef>

typedef unsigned short ushort_t;
typedef unsigned int uint_t;
typedef __attribute__((ext_vector_type(8))) short bf16x8;
typedef __attribute__((ext_vector_type(4))) float f32x4;

#define NB 128
#define NC 128
#define NL 256
#define NH 8
#define HD 16
#define HDV 64
#define NEV 512
#define PHALF 4194304   // elements per conv1 partial half (128*256*128)

__device__ __forceinline__ ushort_t f2bf(float f) {
    uint_t u = __float_as_uint(f);
    u += 0x7fffu + ((u >> 16) & 1u);
    return (ushort_t)(u >> 16);
}
__device__ __forceinline__ float bf2f(ushort_t s) {
    return __uint_as_float(((uint_t)s) << 16);
}
// single-instruction packed f32->bf16 (RNE), lo in low 16 bits
__device__ __forceinline__ uint_t pack2(float lo, float hi) {
    uint_t r;
    asm("v_cvt_pk_bf16_f32 %0, %1, %2" : "=v"(r) : "v"(lo), "v"(hi));
    return r;
}

// ---------------- pack helpers (device) ----------------
template<int CIN, int GRP>
__device__ __forceinline__ void wpack_one(int idx, const float* __restrict__ w,
                                          short* __restrict__ wp) {
    constexpr int LG = (GRP == 4) ? 2 : 1;
    int j    = idx & 7;
    int r    = (idx >> 3) & (GRP - 1);
    int lane = (idx >> (3 + LG)) & 63;
    int gidx = (idx >> (9 + LG)) & ((8 / GRP) - 1);
    int tc   = idx >> 12;
    int tap  = tc % 9;
    int ch   = tc / 9;
    int co   = (gidx * GRP + r) * 16 + (lane & 15);
    int ci   = ch * 32 + (lane >> 4) * 8 + j;
    wp[idx] = (short)f2bf(w[((size_t)co * CIN + ci) * 9 + tap]);
}

// ---------------- K0: merged conv-weight pack (conv1 GRP=4, conv2 GRP=2)
__global__ __launch_bounds__(256) void k_wpack_conv(const float* __restrict__ pwo,
                                                    const float* __restrict__ fw,
                                                    short* __restrict__ wp1,
                                                    short* __restrict__ wp2) {
    const int bid = blockIdx.x;
    if (bid < 2304) {
        int idx = bid * 256 + threadIdx.x;          // NEV*1152 = 589824 exactly
        wpack_one<NEV, 4>(idx, pwo, wp1);
    } else {
        int idx = (bid - 2304) * 256 + threadIdx.x; // NC*1152 = 147456 exactly
        wpack_one<NC, 2>(idx, fw, wp2);
    }
}

// ---------------- K0b: merged projection-weight pack (q, k, v)
__device__ __forceinline__ void qkvpack_one(int idx, const float* __restrict__ w,
                                            short* __restrict__ wp) {
    int j    = idx & 7;
    int lane = (idx >> 3) & 63;
    int ch   = (idx >> 9) & 3;
    int rt   = idx >> 11;
    int n = lane & 15, g = lane >> 4;
    wp[idx] = (short)f2bf(w[(size_t)(rt*16 + n)*128 + ch*32 + g*8 + j]);
}
__global__ __launch_bounds__(256) void k_wpack_qkv3(const float* __restrict__ pwq,
                                                    const float* __restrict__ pwk,
                                                    const float* __restrict__ pwv,
                                                    short* __restrict__ wpq,
                                                    short* __restrict__ wpk,
                                                    short* __restrict__ wpv) {
    const int bid = blockIdx.x;
    if (bid < 64) {
        qkvpack_one(bid * 256 + threadIdx.x, pwq, wpq);          // 128*128 = 16384
    } else if (bid < 128) {
        qkvpack_one((bid - 64) * 256 + threadIdx.x, pwk, wpk);
    } else {
        qkvpack_one((bid - 128) * 256 + threadIdx.x, pwv, wpv);  // 512*128 = 65536
    }
}

// ---------------- K0c: transpose X (NCHW f32) -> xbf (NHWC bf16), once.
__global__ __launch_bounds__(256) void k_xpose(const float* __restrict__ x,
                                               ushort_t* __restrict__ xbf) {
    const int half = blockIdx.x, b = blockIdx.y, t = threadIdx.x;
    const float* src = x + (size_t)b*NC*NL + (size_t)half*64*NL + t;
    uint_t* dst = (uint_t*)(xbf + ((size_t)b*NL + t)*NC + half*64);
    #pragma unroll
    for (int k8 = 0; k8 < 8; ++k8) {
        uint4 u;
        u.x = pack2(src[(k8*8+0)*NL], src[(k8*8+1)*NL]);
        u.y = pack2(src[(k8*8+2)*NL], src[(k8*8+3)*NL]);
        u.z = pack2(src[(k8*8+4)*NL], src[(k8*8+5)*NL]);
        u.w = pack2(src[(k8*8+6)*NL], src[(k8*8+7)*NL]);
        *(uint4*)(dst + k8*4) = u;
    }
}

// ---------------- K1: full-MFMA position attention. Block = (h, b), 8 waves x 32 q.
__global__ __launch_bounds__(512, 4) void k_pos_mfma(
    const ushort_t* __restrict__ xbf,
    const short* __restrict__ wpq, const short* __restrict__ wpk,
    const short* __restrict__ wpv,
    const float* __restrict__ bq, const float* __restrict__ bk,
    const float* __restrict__ bv,
    ushort_t* __restrict__ att)
{
    const int h = blockIdx.x, b = blockIdx.y;
    const int t = threadIdx.x;
    const int lane = t & 63, w = t >> 6;
    const int n = lane & 15, g = lane >> 4;

    __shared__ __align__(16) short lds[26112];   // 52,224 B

    const f32x4 z4 = {0.f, 0.f, 0.f, 0.f};
    f32x4 qacc[2], kacc[2], vacc[4][2];
    #pragma unroll
    for (int ct = 0; ct < 2; ++ct) { qacc[ct] = z4; kacc[ct] = z4; }
    #pragma unroll
    for (int vt = 0; vt < 4; ++vt)
        #pragma unroll
        for (int ct = 0; ct < 2; ++ct) vacc[vt][ct] = z4;

    const ushort_t* xr = xbf + ((size_t)(b*NL + w*32 + n))*NC;

    #pragma unroll 2
    for (int ch = 0; ch < 4; ++ch) {
        bf16x8 xb[2];
        #pragma unroll
        for (int ct = 0; ct < 2; ++ct)
            xb[ct] = *(const bf16x8*)(xr + ct*16*NC + ch*32 + g*8);
        const size_t fo = ((size_t)((h*4 + ch)*64) + lane) * 8;
        {
            bf16x8 aq = *(const bf16x8*)(wpq + fo);
            #pragma unroll
            for (int ct = 0; ct < 2; ++ct)
                qacc[ct] = __builtin_amdgcn_mfma_f32_16x16x32_bf16(aq, xb[ct], qacc[ct], 0, 0, 0);
        }
        {
            bf16x8 ak = *(const bf16x8*)(wpk + fo);
            #pragma unroll
            for (int ct = 0; ct < 2; ++ct)
                kacc[ct] = __builtin_amdgcn_mfma_f32_16x16x32_bf16(ak, xb[ct], kacc[ct], 0, 0, 0);
        }
        #pragma unroll
        for (int vt = 0; vt < 4; ++vt) {
            bf16x8 av = *(const bf16x8*)(wpv + ((size_t)((((h*4 + vt)*4) + ch)*64) + lane) * 8);
            #pragma unroll
            for (int ct = 0; ct < 2; ++ct)   // SWAPPED: D[l][dv]
                vacc[vt][ct] = __builtin_amdgcn_mfma_f32_16x16x32_bf16(xb[ct], av, vacc[vt][ct], 0, 0, 0);
        }
    }

    uint_t qu01[2], qu23[2];
    {
        float bqv[4], bkv[4];
        #pragma unroll
        for (int r = 0; r < 4; ++r) {
            bqv[r] = bq[h*16 + g*4 + r];
            bkv[r] = bk[h*16 + g*4 + r];
        }
        #pragma unroll
        for (int ct = 0; ct < 2; ++ct) {
            qu01[ct] = pack2(qacc[ct][0] + bqv[0], qacc[ct][1] + bqv[1]);
            qu23[ct] = pack2(qacc[ct][2] + bqv[2], qacc[ct][3] + bqv[3]);
            uint2 kp;
            kp.x = pack2(kacc[ct][0] + bkv[0], kacc[ct][1] + bkv[1]);
            kp.y = pack2(kacc[ct][2] + bkv[2], kacc[ct][3] + bkv[3]);
            *(uint2*)&lds[(w*32 + ct*16 + n)*16 + g*4] = kp;
        }
        #pragma unroll
        for (int vt = 0; vt < 4; ++vt) {
            const float bvv = bv[h*64 + vt*16 + n];
            #pragma unroll
            for (int ct = 0; ct < 2; ++ct) {
                uint2 vp;
                vp.x = pack2(vacc[vt][ct][0] + bvv, vacc[vt][ct][1] + bvv);
                vp.y = pack2(vacc[vt][ct][2] + bvv, vacc[vt][ct][3] + bvv);
                *(uint2*)&lds[9216 + (vt*16 + n)*264 + w*32 + ct*16 + g*4] = vp;
            }
        }
    }
    __syncthreads();

    const int a0 = (n + 32*(g & 1)) * 4;
    #pragma unroll 1
    for (int qt = 0; qt < 2; ++qt) {
        union { uint_t u[4]; bf16x8 v; } qfu;
        qfu.u[0] = (uint_t)__builtin_amdgcn_ds_bpermute(a0,      (int)qu01[qt]);
        qfu.u[1] = (uint_t)__builtin_amdgcn_ds_bpermute(a0,      (int)qu23[qt]);
        qfu.u[2] = (uint_t)__builtin_amdgcn_ds_bpermute(a0 + 64, (int)qu01[qt]);
        qfu.u[3] = (uint_t)__builtin_amdgcn_ds_bpermute(a0 + 64, (int)qu23[qt]);
        if (g >= 2) { qfu.u[0] = 0; qfu.u[1] = 0; qfu.u[2] = 0; qfu.u[3] = 0; }
        bf16x8 qf = qfu.v;

        f32x4 s[16];
        #pragma unroll
        for (int kt = 0; kt < 16; ++kt) {
            bf16x8 kf = (bf16x8){0,0,0,0,0,0,0,0};
            if (g < 2) kf = *(const bf16x8*)&lds[(kt*16 + n)*16 + g*8];
            s[kt] = __builtin_amdgcn_mfma_f32_16x16x32_bf16(kf, qf, z4, 0, 0, 0);
        }
        float d0 = 0.f, d1 = 0.f, d2 = 0.f, d3 = 0.f;
        #pragma unroll
        for (int kt = 0; kt < 16; ++kt) {
            float e0 = exp2f(s[kt][0] * 0.36067376022224085f);
            float e1 = exp2f(s[kt][1] * 0.36067376022224085f);
            float e2 = exp2f(s[kt][2] * 0.36067376022224085f);
            float e3 = exp2f(s[kt][3] * 0.36067376022224085f);
            s[kt][0] = e0; s[kt][1] = e1; s[kt][2] = e2; s[kt][3] = e3;
            d0 += e0; d1 += e1; d2 += e2; d3 += e3;
        }
        float den = (d0 + d1) + (d2 + d3);
        den += __shfl_xor(den, 16);
        den += __shfl_xor(den, 32);
        const float inv = 1.f / den;

        f32x4 oacc[4] = {z4, z4, z4, z4};
        #pragma unroll
        for (int c2 = 0; c2 < 8; ++c2) {
            #pragma unroll
            for (int u = 0; u < 2; ++u) {
                const int kt = 2*c2 + u;
                uint2 pp;
                pp.x = pack2(s[kt][0], s[kt][1]);
                pp.y = pack2(s[kt][2], s[kt][3]);
                *(uint2*)&lds[4096 + w*640 + n*40 + u*16 + g*4] = pp;
            }
            bf16x8 pf = *(const bf16x8*)&lds[4096 + w*640 + n*40 + g*8];
            #pragma unroll
            for (int vt = 0; vt < 4; ++vt) {
                bf16x8 av = *(const bf16x8*)&lds[9216 + (vt*16 + n)*264 + c2*32 + g*8];
                oacc[vt] = __builtin_amdgcn_mfma_f32_16x16x32_bf16(av, pf, oacc[vt], 0, 0, 0);
            }
        }
        ushort_t* ap = att + (((size_t)b*NL + (w*32 + qt*16 + n))*NEV + h*HDV + g*4);
        #pragma unroll
        for (int vt = 0; vt < 4; ++vt) {
            uint2 op;
            op.x = pack2(oacc[vt][0]*inv, oacc[vt][1]*inv);
            op.y = pack2(oacc[vt][2]*inv, oacc[vt][3]*inv);
            *(uint2*)(ap + vt*16) = op;
        }
    }
}

// ---------------- K2: conv1 (3x3, 512->128) ci+l-split, T14 + depth-3 A pipeline.
// grid (4, NB): blockIdx.x = kc*2 + lh. Block = 128co x 128l x 256ci,
// 4 waves (2co x 2l), wave tile 64co x 64l. LDS: 10-row haloed image dbuf.
// (Measured-best structure: 53.3 us, MfmaUtil ~27%.)
__global__ __launch_bounds__(256, 2) void k_conv_ci(
    const ushort_t* __restrict__ att, const short* __restrict__ wp,
    ushort_t* __restrict__ P)
{
    const int kc = blockIdx.x >> 1, lh = blockIdx.x & 1, b = blockIdx.y;
    const int t = threadIdx.x;
    const int lane = t & 63, w = t >> 6;
    const int wr = w >> 1, wc = w & 1;
    const int n = lane & 15, gl = lane >> 4;
    const int y0 = lh * 8;

    __shared__ __align__(16) short ims[2][5760];   // 2 x 11.25 KB

    {
        bf16x8 z = {0,0,0,0,0,0,0,0};
        bf16x8* p = (bf16x8*)&ims[0][0];
        for (int i = t; i < 1440; i += 256) p[i] = z;
    }

    f32x4 acc[4][4];
    #pragma unroll
    for (int i = 0; i < 4; ++i)
        #pragma unroll
        for (int j = 0; j < 4; ++j) acc[i][j] = (f32x4){0.f,0.f,0.f,0.f};

    const int gg1 = t & 3,        xx1 = (t >> 2) & 15,        yp1 = t >> 6;
    const int id2 = t + 256;
    const int gg2 = id2 & 3,      xx2 = (id2 >> 2) & 15,      yp2 = id2 >> 6;
    const int id3 = t + 512;
    const int gg3 = id3 & 3,      xx3 = (id3 >> 2) & 15,      yp3 = id3 >> 6;
    const bool has3 = (t < 128);
    const int y1 = y0 - 1 + yp1, y2 = y0 - 1 + yp2, y3 = y0 - 1 + yp3;
    const bool ok1 = (y1 >= 0) && (y1 < 16);
    const bool ok2 = (y2 >= 0) && (y2 < 16);
    const bool ok3 = has3 && (y3 >= 0) && (y3 < 16);
    const ushort_t* src1 = att + ((size_t)(b*NL + y1*16 + xx1))*NEV + kc*256 + gg1*8;
    const ushort_t* src2 = att + ((size_t)(b*NL + y2*16 + xx2))*NEV + kc*256 + gg2*8;
    const ushort_t* src3 = att + ((size_t)(b*NL + y3*16 + xx3))*NEV + kc*256 + gg3*8;
    const int slot1 = ((yp1*4 + gg1)*18 + xx1 + 1) * 8;
    const int slot2 = ((yp2*4 + gg2)*18 + xx2 + 1) * 8;
    const int slot3 = ((yp3*4 + gg3)*18 + xx3 + 1) * 8;

    bf16x8 v1 = {0,0,0,0,0,0,0,0}, v2 = v1, v3 = v1;
    if (ok1) v1 = *(const bf16x8*)src1;
    if (ok2) v2 = *(const bf16x8*)src2;
    if (ok3) v3 = *(const bf16x8*)src3;

    const short* wpl = wp + (size_t)lane * 32;
    auto Aaddr = [&](int ch16, int tap) {
        return (const bf16x8*)(wpl + ((size_t)((ch16*9 + tap)*2 + wr)) * 2048);
    };

    bf16x8 Abuf[3][4];            // static-indexed (tap loop fully unrolled)
    bf16x8 Bc[4], Bn[4];
    #pragma unroll
    for (int i = 0; i < 4; ++i) { Bc[i] = (bf16x8){0,0,0,0,0,0,0,0}; Bn[i] = Bc[i]; }

    __syncthreads();              // zero-init done

    #pragma unroll 1
    for (int ch = 0; ch < 8; ++ch) {
        const int ch16 = kc*8 + ch;
        short* buf = &ims[ch & 1][0];
        *(bf16x8*)&buf[slot1] = v1;
        *(bf16x8*)&buf[slot2] = v2;
        if (has3) *(bf16x8*)&buf[slot3] = v3;
        __syncthreads();                     // image ready
        if (ch < 7) {                        // T14: issue AFTER barrier
            if (ok1) v1 = *(const bf16x8*)(src1 + (ch + 1) * 32);
            if (ok2) v2 = *(const bf16x8*)(src2 + (ch + 1) * 32);
            if (ok3) v3 = *(const bf16x8*)(src3 + (ch + 1) * 32);
        }
        #pragma unroll
        for (int p = 0; p < 3; ++p) {
            const bf16x8* ap = Aaddr(ch16, p);
            #pragma unroll
            for (int rt = 0; rt < 4; ++rt) Abuf[p][rt] = ap[rt];
        }
        #pragma unroll
        for (int ct = 0; ct < 4; ++ct)
            Bc[ct] = *(const bf16x8*)&buf[(((wc*4 + ct)*4 + gl)*18 + n) * 8];

        #pragma unroll
        for (int tap = 0; tap < 9; ++tap) {
            if (tap < 8) {
                const int dy = (tap + 1) / 3, dx = (tap + 1) % 3;
                #pragma unroll
                for (int ct = 0; ct < 4; ++ct)
                    Bn[ct] = *(const bf16x8*)&buf[(((wc*4 + ct + dy)*4 + gl)*18 + n + dx) * 8];
            }
            #pragma unroll
            for (int rt = 0; rt < 4; ++rt)
                #pragma unroll
                for (int ct = 0; ct < 4; ++ct)
                    acc[rt][ct] = __builtin_amdgcn_mfma_f32_16x16x32_bf16(
                        Abuf[tap % 3][rt], Bc[ct], acc[rt][ct], 0, 0, 0);
            if (tap + 3 < 9) {
                const bf16x8* ap = Aaddr(ch16, tap + 3);
                #pragma unroll
                for (int rt = 0; rt < 4; ++rt) Abuf[tap % 3][rt] = ap[rt];
            }
            #pragma unroll
            for (int i = 0; i < 4; ++i)
                if (tap < 8) Bc[i] = Bn[i];
        }
    }

    ushort_t* Pb = P + (size_t)kc * PHALF + (size_t)b * NL * NC;
    #pragma unroll
    for (int rt = 0; rt < 4; ++rt) {
        const int co0 = wr*64 + rt*16 + gl*4;
        #pragma unroll
        for (int ct = 0; ct < 4; ++ct) {
            const int l = lh*128 + wc*64 + ct*16 + n;
            uint2 u;
            u.x = pack2(acc[rt][ct][0], acc[rt][ct][1]);
            u.y = pack2(acc[rt][ct][2], acc[rt][ct][3]);
            *(uint2*)(Pb + (size_t)l*NC + co0) = u;
        }
    }
}

// ---------------- K4: conv2 (3x3, 128->128) co+l-split, T14 + depth-3 A pipeline.
// grid (4, NB): blockIdx.x = kc*2 + lh (kc = 64-co half, lh = 128-l half).
// 4 waves (2co x 2l), wave tile 32co x 64l. comb is bf16 NHWC -> direct staging.
__global__ __launch_bounds__(256, 2) void k_conv_co(
    const ushort_t* __restrict__ comb, const short* __restrict__ wp,
    const float* __restrict__ bias, float* __restrict__ out)
{
    const int kc = blockIdx.x >> 1, lh = blockIdx.x & 1, b = blockIdx.y;
    const int t = threadIdx.x;
    const int lane = t & 63, w = t >> 6;
    const int wr = w >> 1, wc = w & 1;
    const int n = lane & 15, gl = lane >> 4;
    const int y0 = lh * 8;

    __shared__ __align__(16) short ims[2][5760];

    {
        bf16x8 z = {0,0,0,0,0,0,0,0};
        bf16x8* p = (bf16x8*)&ims[0][0];
        for (int i = t; i < 1440; i += 256) p[i] = z;
    }

    f32x4 acc[2][4];
    #pragma unroll
    for (int i = 0; i < 2; ++i)
        #pragma unroll
        for (int j = 0; j < 4; ++j) acc[i][j] = (f32x4){0.f,0.f,0.f,0.f};

    const int gg1 = t & 3,        xx1 = (t >> 2) & 15,        yp1 = t >> 6;
    const int id2 = t + 256;
    const int gg2 = id2 & 3,      xx2 = (id2 >> 2) & 15,      yp2 = id2 >> 6;
    const int id3 = t + 512;
    const int gg3 = id3 & 3,      xx3 = (id3 >> 2) & 15,      yp3 = id3 >> 6;
    const bool has3 = (t < 128);
    const int y1 = y0 - 1 + yp1, y2 = y0 - 1 + yp2, y3 = y0 - 1 + yp3;
    const bool ok1 = (y1 >= 0) && (y1 < 16);
    const bool ok2 = (y2 >= 0) && (y2 < 16);
    const bool ok3 = has3 && (y3 >= 0) && (y3 < 16);
    const ushort_t* s1 = comb + ((size_t)(b*NL + y1*16 + xx1))*NC + gg1*8;
    const ushort_t* s2 = comb + ((size_t)(b*NL + y2*16 + xx2))*NC + gg2*8;
    const ushort_t* s3 = comb + ((size_t)(b*NL + y3*16 + xx3))*NC + gg3*8;
    const int slot1 = ((yp1*4 + gg1)*18 + xx1 + 1) * 8;
    const int slot2 = ((yp2*4 + gg2)*18 + xx2 + 1) * 8;
    const int slot3 = ((yp3*4 + gg3)*18 + xx3 + 1) * 8;

    bf16x8 v1 = {0,0,0,0,0,0,0,0}, v2 = v1, v3 = v1;
    if (ok1) v1 = *(const bf16x8*)s1;
    if (ok2) v2 = *(const bf16x8*)s2;
    if (ok3) v3 = *(const bf16x8*)s3;

    const short* wpl = wp + (size_t)lane * 16;
    auto Aaddr = [&](int ch, int tap) {
        return (const bf16x8*)(wpl + ((size_t)((ch*9 + tap)*4 + kc*2 + wr)) * 1024);
    };

    bf16x8 Abuf[3][2];
    bf16x8 Bc[4], Bn[4];
    #pragma unroll
    for (int i = 0; i < 4; ++i) { Bc[i] = (bf16x8){0,0,0,0,0,0,0,0}; Bn[i] = Bc[i]; }

    __syncthreads();

    #pragma unroll 1
    for (int ch = 0; ch < 4; ++ch) {
        short* buf = &ims[ch & 1][0];
        *(bf16x8*)&buf[slot1] = v1;
        *(bf16x8*)&buf[slot2] = v2;
        if (has3) *(bf16x8*)&buf[slot3] = v3;
        __syncthreads();
        if (ch < 3) {                        // T14: issue after barrier
            if (ok1) v1 = *(const bf16x8*)(s1 + (ch + 1) * 32);
            if (ok2) v2 = *(const bf16x8*)(s2 + (ch + 1) * 32);
            if (ok3) v3 = *(const bf16x8*)(s3 + (ch + 1) * 32);
        }
        #pragma unroll
        for (int p = 0; p < 3; ++p) {
            const bf16x8* ap = Aaddr(ch, p);
            #pragma unroll
            for (int rt = 0; rt < 2; ++rt) Abuf[p][rt] = ap[rt];
        }
        #pragma unroll
        for (int ct = 0; ct < 4; ++ct)
            Bc[ct] = *(const bf16x8*)&buf[(((wc*4 + ct)*4 + gl)*18 + n) * 8];

        #pragma unroll
        for (int tap = 0; tap < 9; ++tap) {
            if (tap < 8) {
                const int dy = (tap + 1) / 3, dx = (tap + 1) % 3;
                #pragma unroll
                for (int ct = 0; ct < 4; ++ct)
                    Bn[ct] = *(const bf16x8*)&buf[(((wc*4 + ct + dy)*4 + gl)*18 + n + dx) * 8];
            }
            #pragma unroll
            for (int rt = 0; rt < 2; ++rt)
                #pragma unroll
                for (int ct = 0; ct < 4; ++ct)
                    acc[rt][ct] = __builtin_amdgcn_mfma_f32_16x16x32_bf16(
                        Abuf[tap % 3][rt], Bc[ct], acc[rt][ct], 0, 0, 0);
            if (tap + 3 < 9) {
                const bf16x8* ap = Aaddr(ch, tap + 3);
                #pragma unroll
                for (int rt = 0; rt < 2; ++rt) Abuf[tap % 3][rt] = ap[rt];
            }
            #pragma unroll
            for (int i = 0; i < 4; ++i)
                if (tap < 8) Bc[i] = Bn[i];
        }
    }

    #pragma unroll
    for (int rt = 0; rt < 2; ++rt) {
        const int co0 = kc*64 + wr*32 + rt*16 + gl*4;
        const float c0 = bias[co0+0], c1 = bias[co0+1],
                    c2 = bias[co0+2], c3 = bias[co0+3];
        #pragma unroll
        for (int ct = 0; ct < 4; ++ct) {
            const int l = lh*128 + wc*64 + ct*16 + n;
            f32x4 a = acc[rt][ct];
            out[((size_t)b*NC + co0+0)*NL + l] = c0 + a[0];
            out[((size_t)b*NC + co0+1)*NL + l] = c1 + a[1];
            out[((size_t)b*NC + co0+2)*NL + l] = c2 + a[2];
            out[((size_t)b*NC + co0+3)*NL + l] = c3 + a[3];
        }
    }
}

// ---------------- K3: channel attention + fold conv1 partials + pos residual + fusion.
// comb output is bf16 NHWC (feeds conv2's direct staging).
#define NLP 260
__global__ __launch_bounds__(256) void k_cha(
    const float* __restrict__ xc,
    const float* __restrict__ cwq, const float* __restrict__ cbq,
    const float* __restrict__ cwk, const float* __restrict__ cbk,
    const float* __restrict__ cwv, const float* __restrict__ cbv,
    const float* __restrict__ cwo, const float* __restrict__ cbo,
    const float* __restrict__ gamma,
    const ushort_t* __restrict__ P, const float* __restrict__ qpos,
    const float* __restrict__ pbo, const float* __restrict__ gpos,
    ushort_t* __restrict__ comb)
{
    const int h = blockIdx.x, b = blockIdx.y, t = threadIdx.x;
    __shared__ float qh[16][NLP];
    __shared__ float G_s[16][17];
    __shared__ float S_s[16];
    __shared__ float wq_s[128], bq_s[128], wk_s[128], bk_s[128], wv_s[128], bv_s[128];
    __shared__ float A_s[128][17];
    __shared__ float B_s[128];
    __shared__ float M_s[16][17];
    __shared__ float c_s[16];

    #pragma unroll
    for (int j = 0; j < 16; ++j)
        qh[j][t] = xc[((size_t)b*NC + h*16 + j)*NL + t];
    if (t < 128) {
        const int k = h*128 + t;
        wq_s[t] = cwq[k]; bq_s[t] = cbq[k];
        wk_s[t] = cwk[k]; bk_s[t] = cbk[k];
        wv_s[t] = cwv[k]; bv_s[t] = cbv[k];
    }
    __syncthreads();
    {
        const int i = t >> 4, j = t & 15;
        const float4* qi = (const float4*)qh[i];
        const float4* qj = (const float4*)qh[j];
        float gg = 0.f;
        for (int l4 = 0; l4 < NL/4; ++l4) {
            float4 a = qi[l4], c = qj[l4];
            gg = fmaf(a.x,c.x,fmaf(a.y,c.y,fmaf(a.z,c.z,fmaf(a.w,c.w,gg))));
        }
        G_s[i][j] = gg;
    }
    if (t < 16) {
        const float4* qi = (const float4*)qh[t];
        float s = 0.f;
        for (int l4 = 0; l4 < NL/4; ++l4) { float4 a = qi[l4]; s += a.x + a.y + a.z + a.w; }
        S_s[t] = s;
    }
    __syncthreads();
    if (t < 128) {
        const int c2 = t, cg = c2 >> 3;
        const float wqc = wq_s[c2], bqc = bq_s[c2];
        float Pv[16];
        #pragma unroll
        for (int j = 0; j < 16; ++j) Pv[j] = wqc*G_s[cg][j] + bqc*S_s[j];
        const float Qc = wqc*S_s[cg] + bqc*256.0f;
        float mx = -3.0e38f;
        #pragma unroll
        for (int dg = 0; dg < 16; ++dg) {
            #pragma unroll
            for (int dj = 0; dj < 8; ++dj) {
                const int d = dg*8 + dj;
                float s = wk_s[d]*Pv[dg] + bk_s[d]*Qc;
                mx = fmaxf(mx, s);
            }
        }
        float A[16];
        #pragma unroll
        for (int j = 0; j < 16; ++j) A[j] = 0.f;
        float Bv = 0.f, den = 0.f;
        #pragma unroll
        for (int dg = 0; dg < 16; ++dg) {
            #pragma unroll
            for (int dj = 0; dj < 8; ++dj) {
                const int d = dg*8 + dj;
                float s = wk_s[d]*Pv[dg] + bk_s[d]*Qc;
                float e = __expf((s - mx) * 0.0625f);
                den += e;
                A[dg] = fmaf(e, wv_s[d], A[dg]);
                Bv = fmaf(e, bv_s[d], Bv);
            }
        }
        const float inv = 1.f / den;
        #pragma unroll
        for (int j = 0; j < 16; ++j) A_s[c2][j] = A[j]*inv;
        B_s[c2] = Bv*inv;
    }
    __syncthreads();
    {
        const int cl = t >> 4, j = t & 15;
        const int cp = h*16 + cl;
        float m = 0.f;
        #pragma unroll
        for (int hp = 0; hp < 8; ++hp)
            m = fmaf(cwo[cp*8+hp], A_s[cl*8+hp][j], m);
        M_s[cl][j] = m;
        if (j == 0) {
            float cc = cbo[cp];
            #pragma unroll
            for (int hp = 0; hp < 8; ++hp)
                cc = fmaf(cwo[cp*8+hp], B_s[cl*8+hp], cc);
            c_s[cl] = cc;
        }
    }
    __syncthreads();
    {
        const float g  = gamma[0];
        const float gp = gpos[0];
        const int l = t;
        float cv[16];
        #pragma unroll
        for (int cl = 0; cl < 16; ++cl) {
            float a = c_s[cl];
            #pragma unroll
            for (int j = 0; j < 16; ++j)
                a = fmaf(M_s[cl][j], qh[j][l], a);
            cv[cl] = a;
        }
        const ushort_t* p0 = P + ((size_t)b*NL + l)*NC + h*16;
        const ushort_t* p1 = p0 + PHALF;
        const float* qp = qpos + ((size_t)b*NC + h*16)*NL + l;
        #pragma unroll
        for (int q = 0; q < 4; ++q) {
            uint2 u0 = *(const uint2*)(p0 + 4*q);
            uint2 u1 = *(const uint2*)(p1 + 4*q);
            float s0 = bf2f((ushort_t)(u0.x & 0xffffu)) + bf2f((ushort_t)(u1.x & 0xffffu));
            float s1 = bf2f((ushort_t)(u0.x >> 16))     + bf2f((ushort_t)(u1.x >> 16));
            float s2 = bf2f((ushort_t)(u0.y & 0xffffu)) + bf2f((ushort_t)(u1.y & 0xffffu));
            float s3 = bf2f((ushort_t)(u0.y >> 16))     + bf2f((ushort_t)(u1.y >> 16));
            cv[4*q+0] = 0.5f*(qp[(4*q+0)*NL] + gp*(pbo[h*16+4*q+0] + s0) + qh[4*q+0][l] + g*cv[4*q+0]);
            cv[4*q+1] = 0.5f*(qp[(4*q+1)*NL] + gp*(pbo[h*16+4*q+1] + s1) + qh[4*q+1][l] + g*cv[4*q+1]);
            cv[4*q+2] = 0.5f*(qp[(4*q+2)*NL] + gp*(pbo[h*16+4*q+2] + s2) + qh[4*q+2][l] + g*cv[4*q+2]);
            cv[4*q+3] = 0.5f*(qp[(4*q+3)*NL] + gp*(pbo[h*16+4*q+3] + s3) + qh[4*q+3][l] + g*cv[4*q+3]);
        }
        ushort_t* cp = comb + ((size_t)b*NL + l)*NC + h*16;
        uint4 o0, o1;
        o0.x = pack2(cv[0],  cv[1]);   o0.y = pack2(cv[2],  cv[3]);
        o0.z = pack2(cv[4],  cv[5]);   o0.w = pack2(cv[6],  cv[7]);
        o1.x = pack2(cv[8],  cv[9]);   o1.y = pack2(cv[10], cv[11]);
        o1.z = pack2(cv[12], cv[13]);  o1.w = pack2(cv[14], cv[15]);
        *(uint4*)cp       = o0;
        *(uint4*)(cp + 8) = o1;
    }
}

extern "C" void kernel_launch(void* const* d_in, const int* in_sizes, int n_in,
                              void* d_out, int out_size, void* d_ws, size_t ws_size,
                              hipStream_t stream)
{
    const float* qpos = (const float*)d_in[0];
    const float* qcha = (const float*)d_in[1];
    const float* pwq  = (const float*)d_in[2];
    const float* pbq  = (const float*)d_in[3];
    const float* pwk  = (const float*)d_in[4];
    const float* pbk  = (const float*)d_in[5];
    const float* pwv  = (const float*)d_in[6];
    const float* pbv  = (const float*)d_in[7];
    const float* pwo  = (const float*)d_in[8];
    const float* pbo  = (const float*)d_in[9];
    const float* gpos = (const float*)d_in[10];
    const float* cwq  = (const float*)d_in[11];
    const float* cbq  = (const float*)d_in[12];
    const float* cwk  = (const float*)d_in[13];
    const float* cbk  = (const float*)d_in[14];
    const float* cwv  = (const float*)d_in[15];
    const float* cbv  = (const float*)d_in[16];
    const float* cwo  = (const float*)d_in[17];
    const float* cbo  = (const float*)d_in[18];
    const float* gcha = (const float*)d_in[19];
    const float* fw   = (const float*)d_in[20];
    const float* fb   = (const float*)d_in[21];
    float* outp = (float*)d_out;

    char* ws = (char*)d_ws;
    ushort_t* att  = (ushort_t*)ws;                       // 33,554,432 B (NHWC bf16)
    ushort_t* comb = (ushort_t*)ws;                       //  8,388,608 B (bf16 NHWC, overlays att)
    ushort_t* P    = (ushort_t*)(ws + 33554432);          // 16,777,216 B (2 bf16 partial halves)
    ushort_t* xbf  = (ushort_t*)(ws + 33554432);          //  8,388,608 B (overlays P; dead before conv_ci)
    short*    wp1  = (short*)(ws + 50331648);             //  1,179,648 B
    short*    wp2  = (short*)(ws + 51511296);             //    294,912 B
    short*    wpq  = (short*)(ws + 51806208);             //     32,768 B
    short*    wpk  = (short*)(ws + 51838976);             //     32,768 B
    short*    wpv  = (short*)(ws + 51871744);             //    131,072 B

    k_wpack_conv<<<dim3(2880), 256, 0, stream>>>(pwo, fw, wp1, wp2);
    k_wpack_qkv3<<<dim3(384),  256, 0, stream>>>(pwq, pwk, pwv, wpq, wpk, wpv);

    k_xpose<<<dim3(2, NB), 256, 0, stream>>>(qpos, xbf);
    k_pos_mfma<<<dim3(NH, NB), 512, 0, stream>>>(xbf, wpq, wpk, wpv,
                                                 pbq, pbk, pbv, att);
    k_conv_ci<<<dim3(4, NB), 256, 0, stream>>>(att, wp1, P);
    k_cha<<<dim3(NH, NB), 256, 0, stream>>>(qcha, cwq, cbq, cwk, cbk, cwv, cbv,
                                            cwo, cbo, gcha,
                                            P, qpos, pbo, gpos, comb);
    k_conv_co<<<dim3(4, NB), 256, 0, stream>>>(comb, wp2, fb, outp);
}

// Round 18
// 162.044 us; speedup vs baseline: 1.1301x; 1.0019x over previous
//
#include <hip/hip_runtime.h>
#include <cstdint>
#include <cstddef>

typedef unsigned short ushort_t;
typedef unsigned int uint_t;
typedef __attribute__((ext_vector_type(8))) short bf16x8;
typedef __attribute__((ext_vector_type(4))) float f32x4;

#define NB 128
#define NC 128
#define NL 256
#define NH 8
#define HD 16
#define HDV 64
#define NEV 512
#define PHALF 4194304   // elements per conv1 partial half (128*256*128)

__device__ __forceinline__ ushort_t f2bf(float f) {
    uint_t u = __float_as_uint(f);
    u += 0x7fffu + ((u >> 16) & 1u);
    return (ushort_t)(u >> 16);
}
__device__ __forceinline__ float bf2f(ushort_t s) {
    return __uint_as_float(((uint_t)s) << 16);
}
// single-instruction packed f32->bf16 (RNE), lo in low 16 bits
__device__ __forceinline__ uint_t pack2(float lo, float hi) {
    uint_t r;
    asm("v_cvt_pk_bf16_f32 %0, %1, %2" : "=v"(r) : "v"(lo), "v"(hi));
    return r;
}

// ---------------- pack helpers (device) ----------------
template<int CIN, int GRP>
__device__ __forceinline__ void wpack_one(int idx, const float* __restrict__ w,
                                          short* __restrict__ wp) {
    constexpr int LG = (GRP == 4) ? 2 : 1;
    int j    = idx & 7;
    int r    = (idx >> 3) & (GRP - 1);
    int lane = (idx >> (3 + LG)) & 63;
    int gidx = (idx >> (9 + LG)) & ((8 / GRP) - 1);
    int tc   = idx >> 12;
    int tap  = tc % 9;
    int ch   = tc / 9;
    int co   = (gidx * GRP + r) * 16 + (lane & 15);
    int ci   = ch * 32 + (lane >> 4) * 8 + j;
    wp[idx] = (short)f2bf(w[((size_t)co * CIN + ci) * 9 + tap]);
}

// ---------------- K0: merged conv-weight pack (conv1 GRP=4, conv2 GRP=2)
__global__ __launch_bounds__(256) void k_wpack_conv(const float* __restrict__ pwo,
                                                    const float* __restrict__ fw,
                                                    short* __restrict__ wp1,
                                                    short* __restrict__ wp2) {
    const int bid = blockIdx.x;
    if (bid < 2304) {
        int idx = bid * 256 + threadIdx.x;          // NEV*1152 = 589824 exactly
        wpack_one<NEV, 4>(idx, pwo, wp1);
    } else {
        int idx = (bid - 2304) * 256 + threadIdx.x; // NC*1152 = 147456 exactly
        wpack_one<NC, 2>(idx, fw, wp2);
    }
}

// ---------------- K0b: merged projection-weight pack (q, k, v)
__device__ __forceinline__ void qkvpack_one(int idx, const float* __restrict__ w,
                                            short* __restrict__ wp) {
    int j    = idx & 7;
    int lane = (idx >> 3) & 63;
    int ch   = (idx >> 9) & 3;
    int rt   = idx >> 11;
    int n = lane & 15, g = lane >> 4;
    wp[idx] = (short)f2bf(w[(size_t)(rt*16 + n)*128 + ch*32 + g*8 + j]);
}
__global__ __launch_bounds__(256) void k_wpack_qkv3(const float* __restrict__ pwq,
                                                    const float* __restrict__ pwk,
                                                    const float* __restrict__ pwv,
                                                    short* __restrict__ wpq,
                                                    short* __restrict__ wpk,
                                                    short* __restrict__ wpv) {
    const int bid = blockIdx.x;
    if (bid < 64) {
        qkvpack_one(bid * 256 + threadIdx.x, pwq, wpq);          // 128*128 = 16384
    } else if (bid < 128) {
        qkvpack_one((bid - 64) * 256 + threadIdx.x, pwk, wpk);
    } else {
        qkvpack_one((bid - 128) * 256 + threadIdx.x, pwv, wpv);  // 512*128 = 65536
    }
}

// ---------------- K0c: transpose X (NCHW f32) -> xbf (NHWC bf16), once.
__global__ __launch_bounds__(256) void k_xpose(const float* __restrict__ x,
                                               ushort_t* __restrict__ xbf) {
    const int half = blockIdx.x, b = blockIdx.y, t = threadIdx.x;
    const float* src = x + (size_t)b*NC*NL + (size_t)half*64*NL + t;
    uint_t* dst = (uint_t*)(xbf + ((size_t)b*NL + t)*NC + half*64);
    #pragma unroll
    for (int k8 = 0; k8 < 8; ++k8) {
        uint4 u;
        u.x = pack2(src[(k8*8+0)*NL], src[(k8*8+1)*NL]);
        u.y = pack2(src[(k8*8+2)*NL], src[(k8*8+3)*NL]);
        u.z = pack2(src[(k8*8+4)*NL], src[(k8*8+5)*NL]);
        u.w = pack2(src[(k8*8+6)*NL], src[(k8*8+7)*NL]);
        *(uint4*)(dst + k8*4) = u;
    }
}

// ---------------- K1: full-MFMA position attention. Block = (h, b), 8 waves x 32 q.
__global__ __launch_bounds__(512, 4) void k_pos_mfma(
    const ushort_t* __restrict__ xbf,
    const short* __restrict__ wpq, const short* __restrict__ wpk,
    const short* __restrict__ wpv,
    const float* __restrict__ bq, const float* __restrict__ bk,
    const float* __restrict__ bv,
    ushort_t* __restrict__ att)
{
    const int h = blockIdx.x, b = blockIdx.y;
    const int t = threadIdx.x;
    const int lane = t & 63, w = t >> 6;
    const int n = lane & 15, g = lane >> 4;

    __shared__ __align__(16) short lds[26112];   // 52,224 B

    const f32x4 z4 = {0.f, 0.f, 0.f, 0.f};
    f32x4 qacc[2], kacc[2], vacc[4][2];
    #pragma unroll
    for (int ct = 0; ct < 2; ++ct) { qacc[ct] = z4; kacc[ct] = z4; }
    #pragma unroll
    for (int vt = 0; vt < 4; ++vt)
        #pragma unroll
        for (int ct = 0; ct < 2; ++ct) vacc[vt][ct] = z4;

    const ushort_t* xr = xbf + ((size_t)(b*NL + w*32 + n))*NC;

    #pragma unroll 2
    for (int ch = 0; ch < 4; ++ch) {
        bf16x8 xb[2];
        #pragma unroll
        for (int ct = 0; ct < 2; ++ct)
            xb[ct] = *(const bf16x8*)(xr + ct*16*NC + ch*32 + g*8);
        const size_t fo = ((size_t)((h*4 + ch)*64) + lane) * 8;
        {
            bf16x8 aq = *(const bf16x8*)(wpq + fo);
            #pragma unroll
            for (int ct = 0; ct < 2; ++ct)
                qacc[ct] = __builtin_amdgcn_mfma_f32_16x16x32_bf16(aq, xb[ct], qacc[ct], 0, 0, 0);
        }
        {
            bf16x8 ak = *(const bf16x8*)(wpk + fo);
            #pragma unroll
            for (int ct = 0; ct < 2; ++ct)
                kacc[ct] = __builtin_amdgcn_mfma_f32_16x16x32_bf16(ak, xb[ct], kacc[ct], 0, 0, 0);
        }
        #pragma unroll
        for (int vt = 0; vt < 4; ++vt) {
            bf16x8 av = *(const bf16x8*)(wpv + ((size_t)((((h*4 + vt)*4) + ch)*64) + lane) * 8);
            #pragma unroll
            for (int ct = 0; ct < 2; ++ct)   // SWAPPED: D[l][dv]
                vacc[vt][ct] = __builtin_amdgcn_mfma_f32_16x16x32_bf16(xb[ct], av, vacc[vt][ct], 0, 0, 0);
        }
    }

    uint_t qu01[2], qu23[2];
    {
        float bqv[4], bkv[4];
        #pragma unroll
        for (int r = 0; r < 4; ++r) {
            bqv[r] = bq[h*16 + g*4 + r];
            bkv[r] = bk[h*16 + g*4 + r];
        }
        #pragma unroll
        for (int ct = 0; ct < 2; ++ct) {
            qu01[ct] = pack2(qacc[ct][0] + bqv[0], qacc[ct][1] + bqv[1]);
            qu23[ct] = pack2(qacc[ct][2] + bqv[2], qacc[ct][3] + bqv[3]);
            uint2 kp;
            kp.x = pack2(kacc[ct][0] + bkv[0], kacc[ct][1] + bkv[1]);
            kp.y = pack2(kacc[ct][2] + bkv[2], kacc[ct][3] + bkv[3]);
            *(uint2*)&lds[(w*32 + ct*16 + n)*16 + g*4] = kp;
        }
        #pragma unroll
        for (int vt = 0; vt < 4; ++vt) {
            const float bvv = bv[h*64 + vt*16 + n];
            #pragma unroll
            for (int ct = 0; ct < 2; ++ct) {
                uint2 vp;
                vp.x = pack2(vacc[vt][ct][0] + bvv, vacc[vt][ct][1] + bvv);
                vp.y = pack2(vacc[vt][ct][2] + bvv, vacc[vt][ct][3] + bvv);
                *(uint2*)&lds[9216 + (vt*16 + n)*264 + w*32 + ct*16 + g*4] = vp;
            }
        }
    }
    __syncthreads();

    const int a0 = (n + 32*(g & 1)) * 4;
    #pragma unroll 1
    for (int qt = 0; qt < 2; ++qt) {
        union { uint_t u[4]; bf16x8 v; } qfu;
        qfu.u[0] = (uint_t)__builtin_amdgcn_ds_bpermute(a0,      (int)qu01[qt]);
        qfu.u[1] = (uint_t)__builtin_amdgcn_ds_bpermute(a0,      (int)qu23[qt]);
        qfu.u[2] = (uint_t)__builtin_amdgcn_ds_bpermute(a0 + 64, (int)qu01[qt]);
        qfu.u[3] = (uint_t)__builtin_amdgcn_ds_bpermute(a0 + 64, (int)qu23[qt]);
        if (g >= 2) { qfu.u[0] = 0; qfu.u[1] = 0; qfu.u[2] = 0; qfu.u[3] = 0; }
        bf16x8 qf = qfu.v;

        f32x4 s[16];
        #pragma unroll
        for (int kt = 0; kt < 16; ++kt) {
            bf16x8 kf = (bf16x8){0,0,0,0,0,0,0,0};
            if (g < 2) kf = *(const bf16x8*)&lds[(kt*16 + n)*16 + g*8];
            s[kt] = __builtin_amdgcn_mfma_f32_16x16x32_bf16(kf, qf, z4, 0, 0, 0);
        }
        float d0 = 0.f, d1 = 0.f, d2 = 0.f, d3 = 0.f;
        #pragma unroll
        for (int kt = 0; kt < 16; ++kt) {
            float e0 = exp2f(s[kt][0] * 0.36067376022224085f);
            float e1 = exp2f(s[kt][1] * 0.36067376022224085f);
            float e2 = exp2f(s[kt][2] * 0.36067376022224085f);
            float e3 = exp2f(s[kt][3] * 0.36067376022224085f);
            s[kt][0] = e0; s[kt][1] = e1; s[kt][2] = e2; s[kt][3] = e3;
            d0 += e0; d1 += e1; d2 += e2; d3 += e3;
        }
        float den = (d0 + d1) + (d2 + d3);
        den += __shfl_xor(den, 16);
        den += __shfl_xor(den, 32);
        const float inv = 1.f / den;

        f32x4 oacc[4] = {z4, z4, z4, z4};
        #pragma unroll
        for (int c2 = 0; c2 < 8; ++c2) {
            #pragma unroll
            for (int u = 0; u < 2; ++u) {
                const int kt = 2*c2 + u;
                uint2 pp;
                pp.x = pack2(s[kt][0], s[kt][1]);
                pp.y = pack2(s[kt][2], s[kt][3]);
                *(uint2*)&lds[4096 + w*640 + n*40 + u*16 + g*4] = pp;
            }
            bf16x8 pf = *(const bf16x8*)&lds[4096 + w*640 + n*40 + g*8];
            #pragma unroll
            for (int vt = 0; vt < 4; ++vt) {
                bf16x8 av = *(const bf16x8*)&lds[9216 + (vt*16 + n)*264 + c2*32 + g*8];
                oacc[vt] = __builtin_amdgcn_mfma_f32_16x16x32_bf16(av, pf, oacc[vt], 0, 0, 0);
            }
        }
        ushort_t* ap = att + (((size_t)b*NL + (w*32 + qt*16 + n))*NEV + h*HDV + g*4);
        #pragma unroll
        for (int vt = 0; vt < 4; ++vt) {
            uint2 op;
            op.x = pack2(oacc[vt][0]*inv, oacc[vt][1]*inv);
            op.y = pack2(oacc[vt][2]*inv, oacc[vt][3]*inv);
            *(uint2*)(ap + vt*16) = op;
        }
    }
}

// ---------------- K2: conv1 (3x3, 512->128) ci+l-split, global_load_lds DMA staging.
// grid (4, NB): blockIdx.x = kc*2 + lh. Block = 128co x 128l x 256ci,
// 4 waves (2co x 2l), wave tile 64co x 64l.
// LDS: halo-free image [10 yp][4 gg][16 x][8] bf16, double-buffered (20 KB).
// Rows DMA'd wave-uniformly (1 KB per instruction); oob rows stay zero;
// x-halo handled on the read side via clamp + edge-lane mask.
__global__ __launch_bounds__(256, 2) void k_conv_ci(
    const ushort_t* __restrict__ att, const short* __restrict__ wp,
    ushort_t* __restrict__ P)
{
    const int kc = blockIdx.x >> 1, lh = blockIdx.x & 1, b = blockIdx.y;
    const int t = threadIdx.x;
    const int lane = t & 63, w = t >> 6;
    const int wr = w >> 1, wc = w & 1;
    const int n = lane & 15, gl = lane >> 4;
    const int y0 = lh * 8;

    __shared__ __align__(16) short ims[2][5120];   // 2 x 10 KB

    {   // zero both buffers once (oob rows never DMA'd -> stay zero)
        bf16x8 z = {0,0,0,0,0,0,0,0};
        bf16x8* p = (bf16x8*)&ims[0][0];
        for (int i = t; i < 1280; i += 256) p[i] = z;
    }

    f32x4 acc[4][4];
    #pragma unroll
    for (int i = 0; i < 4; ++i)
        #pragma unroll
        for (int j = 0; j < 4; ++j) acc[i][j] = (f32x4){0.f,0.f,0.f,0.f};

    // DMA source base: lane l covers (gg = l>>4, x = l&15) of one image row
    const ushort_t* abase = att + (size_t)b*NL*NEV + kc*256 +
                            (size_t)(lane & 15)*NEV + (lane >> 4)*8;

    // wave-uniform row assignment: wave w owns rows {w, w+4, w+8(<10)}
    auto issue_dma = [&](int ch, int bsel) {
        short* dst0 = &ims[bsel][0];
        #pragma unroll
        for (int rr = 0; rr < 3; ++rr) {
            const int yp = w + rr*4;
            if (yp < 10) {
                const int y = y0 - 1 + yp;
                if (y >= 0 && y < 16) {
                    const ushort_t* src = abase + (size_t)(y*16)*NEV + ch*32;
                    __builtin_amdgcn_global_load_lds(
                        (const __attribute__((address_space(1))) void*)src,
                        (__attribute__((address_space(3))) void*)(dst0 + yp*512),
                        16, 0, 0);
                }
            }
        }
    };

    const short* wpl = wp + (size_t)lane * 32;
    auto Aaddr = [&](int ch16, int tap) {
        return (const bf16x8*)(wpl + ((size_t)((ch16*9 + tap)*2 + wr)) * 2048);
    };
    // B read: row r (0..9), real x = n + dx - 1 (clamped; edge lanes masked)
    auto bload = [&](const short* buf, int r, int xc) -> bf16x8 {
        return *(const bf16x8*)&buf[(r*64 + gl*16 + xc)*8];
    };

    bf16x8 Abuf[3][4];
    bf16x8 Bc[4], Bn[4];
    const bf16x8 zf = {0,0,0,0,0,0,0,0};
    #pragma unroll
    for (int i = 0; i < 4; ++i) { Bc[i] = zf; Bn[i] = zf; }

    __syncthreads();              // zero-init visible to all
    issue_dma(0, 0);              // prefetch chunk 0

    #pragma unroll 1
    for (int ch = 0; ch < 8; ++ch) {
        const int ch16 = kc*8 + ch;
        __syncthreads();          // DMA(ch) landed; prior compute done
        const short* buf = &ims[ch & 1][0];
        // A depth-3 prologue: taps 0,1,2
        #pragma unroll
        for (int p = 0; p < 3; ++p) {
            const bf16x8* ap = Aaddr(ch16, p);
            #pragma unroll
            for (int rt = 0; rt < 4; ++rt) Abuf[p][rt] = ap[rt];
        }
        // B tap0 (dy=0, dx=0 -> x = n-1, lane n==0 masked)
        {
            const int xc = (n == 0) ? 0 : n - 1;
            #pragma unroll
            for (int ct = 0; ct < 4; ++ct)
                Bc[ct] = bload(buf, wc*4 + ct, xc);
            if (n == 0) {
                #pragma unroll
                for (int ct = 0; ct < 4; ++ct) Bc[ct] = zf;
            }
        }

        #pragma unroll
        for (int tap = 0; tap < 9; ++tap) {
            if (tap < 8) {
                const int dy = (tap + 1) / 3, dx = (tap + 1) % 3;
                const int xx = n + dx - 1;
                const int xc = (xx < 0) ? 0 : (xx > 15 ? 15 : xx);
                #pragma unroll
                for (int ct = 0; ct < 4; ++ct)
                    Bn[ct] = bload(buf, wc*4 + ct + dy, xc);
                if (dx == 0) {
                    if (n == 0) {
                        #pragma unroll
                        for (int ct = 0; ct < 4; ++ct) Bn[ct] = zf;
                    }
                } else if (dx == 2) {
                    if (n == 15) {
                        #pragma unroll
                        for (int ct = 0; ct < 4; ++ct) Bn[ct] = zf;
                    }
                }
            }
            #pragma unroll
            for (int rt = 0; rt < 4; ++rt)
                #pragma unroll
                for (int ct = 0; ct < 4; ++ct)
                    acc[rt][ct] = __builtin_amdgcn_mfma_f32_16x16x32_bf16(
                        Abuf[tap % 3][rt], Bc[ct], acc[rt][ct], 0, 0, 0);
            if (tap + 3 < 9) {
                const bf16x8* ap = Aaddr(ch16, tap + 3);
                #pragma unroll
                for (int rt = 0; rt < 4; ++rt) Abuf[tap % 3][rt] = ap[rt];
            }
            if (tap == 5 && ch < 7)
                issue_dma(ch + 1, (ch + 1) & 1);   // rides under taps 6-8 + barrier
            #pragma unroll
            for (int i = 0; i < 4; ++i)
                if (tap < 8) Bc[i] = Bn[i];
        }
    }

    ushort_t* Pb = P + (size_t)kc * PHALF + (size_t)b * NL * NC;
    #pragma unroll
    for (int rt = 0; rt < 4; ++rt) {
        const int co0 = wr*64 + rt*16 + gl*4;
        #pragma unroll
        for (int ct = 0; ct < 4; ++ct) {
            const int l = lh*128 + wc*64 + ct*16 + n;
            uint2 u;
            u.x = pack2(acc[rt][ct][0], acc[rt][ct][1]);
            u.y = pack2(acc[rt][ct][2], acc[rt][ct][3]);
            *(uint2*)(Pb + (size_t)l*NC + co0) = u;
        }
    }
}

// ---------------- K4: conv2 (3x3, 128->128) co+l-split, T14 + depth-3 A pipeline.
__global__ __launch_bounds__(256, 2) void k_conv_co(
    const ushort_t* __restrict__ comb, const short* __restrict__ wp,
    const float* __restrict__ bias, float* __restrict__ out)
{
    const int kc = blockIdx.x >> 1, lh = blockIdx.x & 1, b = blockIdx.y;
    const int t = threadIdx.x;
    const int lane = t & 63, w = t >> 6;
    const int wr = w >> 1, wc = w & 1;
    const int n = lane & 15, gl = lane >> 4;
    const int y0 = lh * 8;

    __shared__ __align__(16) short ims[2][5760];

    {
        bf16x8 z = {0,0,0,0,0,0,0,0};
        bf16x8* p = (bf16x8*)&ims[0][0];
        for (int i = t; i < 1440; i += 256) p[i] = z;
    }

    f32x4 acc[2][4];
    #pragma unroll
    for (int i = 0; i < 2; ++i)
        #pragma unroll
        for (int j = 0; j < 4; ++j) acc[i][j] = (f32x4){0.f,0.f,0.f,0.f};

    const int gg1 = t & 3,        xx1 = (t >> 2) & 15,        yp1 = t >> 6;
    const int id2 = t + 256;
    const int gg2 = id2 & 3,      xx2 = (id2 >> 2) & 15,      yp2 = id2 >> 6;
    const int id3 = t + 512;
    const int gg3 = id3 & 3,      xx3 = (id3 >> 2) & 15,      yp3 = id3 >> 6;
    const bool has3 = (t < 128);
    const int y1 = y0 - 1 + yp1, y2 = y0 - 1 + yp2, y3 = y0 - 1 + yp3;
    const bool ok1 = (y1 >= 0) && (y1 < 16);
    const bool ok2 = (y2 >= 0) && (y2 < 16);
    const bool ok3 = has3 && (y3 >= 0) && (y3 < 16);
    const ushort_t* s1 = comb + ((size_t)(b*NL + y1*16 + xx1))*NC + gg1*8;
    const ushort_t* s2 = comb + ((size_t)(b*NL + y2*16 + xx2))*NC + gg2*8;
    const ushort_t* s3 = comb + ((size_t)(b*NL + y3*16 + xx3))*NC + gg3*8;
    const int slot1 = ((yp1*4 + gg1)*18 + xx1 + 1) * 8;
    const int slot2 = ((yp2*4 + gg2)*18 + xx2 + 1) * 8;
    const int slot3 = ((yp3*4 + gg3)*18 + xx3 + 1) * 8;

    bf16x8 v1 = {0,0,0,0,0,0,0,0}, v2 = v1, v3 = v1;
    if (ok1) v1 = *(const bf16x8*)s1;
    if (ok2) v2 = *(const bf16x8*)s2;
    if (ok3) v3 = *(const bf16x8*)s3;

    const short* wpl = wp + (size_t)lane * 16;
    auto Aaddr = [&](int ch, int tap) {
        return (const bf16x8*)(wpl + ((size_t)((ch*9 + tap)*4 + kc*2 + wr)) * 1024);
    };

    bf16x8 Abuf[3][2];
    bf16x8 Bc[4], Bn[4];
    #pragma unroll
    for (int i = 0; i < 4; ++i) { Bc[i] = (bf16x8){0,0,0,0,0,0,0,0}; Bn[i] = Bc[i]; }

    __syncthreads();

    #pragma unroll 1
    for (int ch = 0; ch < 4; ++ch) {
        short* buf = &ims[ch & 1][0];
        *(bf16x8*)&buf[slot1] = v1;
        *(bf16x8*)&buf[slot2] = v2;
        if (has3) *(bf16x8*)&buf[slot3] = v3;
        __syncthreads();
        if (ch < 3) {                        // T14: issue after barrier
            if (ok1) v1 = *(const bf16x8*)(s1 + (ch + 1) * 32);
            if (ok2) v2 = *(const bf16x8*)(s2 + (ch + 1) * 32);
            if (ok3) v3 = *(const bf16x8*)(s3 + (ch + 1) * 32);
        }
        #pragma unroll
        for (int p = 0; p < 3; ++p) {
            const bf16x8* ap = Aaddr(ch, p);
            #pragma unroll
            for (int rt = 0; rt < 2; ++rt) Abuf[p][rt] = ap[rt];
        }
        #pragma unroll
        for (int ct = 0; ct < 4; ++ct)
            Bc[ct] = *(const bf16x8*)&buf[(((wc*4 + ct)*4 + gl)*18 + n) * 8];

        #pragma unroll
        for (int tap = 0; tap < 9; ++tap) {
            if (tap < 8) {
                const int dy = (tap + 1) / 3, dx = (tap + 1) % 3;
                #pragma unroll
                for (int ct = 0; ct < 4; ++ct)
                    Bn[ct] = *(const bf16x8*)&buf[(((wc*4 + ct + dy)*4 + gl)*18 + n + dx) * 8];
            }
            #pragma unroll
            for (int rt = 0; rt < 2; ++rt)
                #pragma unroll
                for (int ct = 0; ct < 4; ++ct)
                    acc[rt][ct] = __builtin_amdgcn_mfma_f32_16x16x32_bf16(
                        Abuf[tap % 3][rt], Bc[ct], acc[rt][ct], 0, 0, 0);
            if (tap + 3 < 9) {
                const bf16x8* ap = Aaddr(ch, tap + 3);
                #pragma unroll
                for (int rt = 0; rt < 2; ++rt) Abuf[tap % 3][rt] = ap[rt];
            }
            #pragma unroll
            for (int i = 0; i < 4; ++i)
                if (tap < 8) Bc[i] = Bn[i];
        }
    }

    #pragma unroll
    for (int rt = 0; rt < 2; ++rt) {
        const int co0 = kc*64 + wr*32 + rt*16 + gl*4;
        const float c0 = bias[co0+0], c1 = bias[co0+1],
                    c2 = bias[co0+2], c3 = bias[co0+3];
        #pragma unroll
        for (int ct = 0; ct < 4; ++ct) {
            const int l = lh*128 + wc*64 + ct*16 + n;
            f32x4 a = acc[rt][ct];
            out[((size_t)b*NC + co0+0)*NL + l] = c0 + a[0];
            out[((size_t)b*NC + co0+1)*NL + l] = c1 + a[1];
            out[((size_t)b*NC + co0+2)*NL + l] = c2 + a[2];
            out[((size_t)b*NC + co0+3)*NL + l] = c3 + a[3];
        }
    }
}

// ---------------- K3: channel attention + fold conv1 partials + pos residual + fusion.
#define NLP 260
__global__ __launch_bounds__(256) void k_cha(
    const float* __restrict__ xc,
    const float* __restrict__ cwq, const float* __restrict__ cbq,
    const float* __restrict__ cwk, const float* __restrict__ cbk,
    const float* __restrict__ cwv, const float* __restrict__ cbv,
    const float* __restrict__ cwo, const float* __restrict__ cbo,
    const float* __restrict__ gamma,
    const ushort_t* __restrict__ P, const float* __restrict__ qpos,
    const float* __restrict__ pbo, const float* __restrict__ gpos,
    ushort_t* __restrict__ comb)
{
    const int h = blockIdx.x, b = blockIdx.y, t = threadIdx.x;
    __shared__ float qh[16][NLP];
    __shared__ float G_s[16][17];
    __shared__ float S_s[16];
    __shared__ float wq_s[128], bq_s[128], wk_s[128], bk_s[128], wv_s[128], bv_s[128];
    __shared__ float A_s[128][17];
    __shared__ float B_s[128];
    __shared__ float M_s[16][17];
    __shared__ float c_s[16];

    #pragma unroll
    for (int j = 0; j < 16; ++j)
        qh[j][t] = xc[((size_t)b*NC + h*16 + j)*NL + t];
    if (t < 128) {
        const int k = h*128 + t;
        wq_s[t] = cwq[k]; bq_s[t] = cbq[k];
        wk_s[t] = cwk[k]; bk_s[t] = cbk[k];
        wv_s[t] = cwv[k]; bv_s[t] = cbv[k];
    }
    __syncthreads();
    {
        const int i = t >> 4, j = t & 15;
        const float4* qi = (const float4*)qh[i];
        const float4* qj = (const float4*)qh[j];
        float gg = 0.f;
        for (int l4 = 0; l4 < NL/4; ++l4) {
            float4 a = qi[l4], c = qj[l4];
            gg = fmaf(a.x,c.x,fmaf(a.y,c.y,fmaf(a.z,c.z,fmaf(a.w,c.w,gg))));
        }
        G_s[i][j] = gg;
    }
    if (t < 16) {
        const float4* qi = (const float4*)qh[t];
        float s = 0.f;
        for (int l4 = 0; l4 < NL/4; ++l4) { float4 a = qi[l4]; s += a.x + a.y + a.z + a.w; }
        S_s[t] = s;
    }
    __syncthreads();
    if (t < 128) {
        const int c2 = t, cg = c2 >> 3;
        const float wqc = wq_s[c2], bqc = bq_s[c2];
        float Pv[16];
        #pragma unroll
        for (int j = 0; j < 16; ++j) Pv[j] = wqc*G_s[cg][j] + bqc*S_s[j];
        const float Qc = wqc*S_s[cg] + bqc*256.0f;
        float mx = -3.0e38f;
        #pragma unroll
        for (int dg = 0; dg < 16; ++dg) {
            #pragma unroll
            for (int dj = 0; dj < 8; ++dj) {
                const int d = dg*8 + dj;
                float s = wk_s[d]*Pv[dg] + bk_s[d]*Qc;
                mx = fmaxf(mx, s);
            }
        }
        float A[16];
        #pragma unroll
        for (int j = 0; j < 16; ++j) A[j] = 0.f;
        float Bv = 0.f, den = 0.f;
        #pragma unroll
        for (int dg = 0; dg < 16; ++dg) {
            #pragma unroll
            for (int dj = 0; dj < 8; ++dj) {
                const int d = dg*8 + dj;
                float s = wk_s[d]*Pv[dg] + bk_s[d]*Qc;
                float e = __expf((s - mx) * 0.0625f);
                den += e;
                A[dg] = fmaf(e, wv_s[d], A[dg]);
                Bv = fmaf(e, bv_s[d], Bv);
            }
        }
        const float inv = 1.f / den;
        #pragma unroll
        for (int j = 0; j < 16; ++j) A_s[c2][j] = A[j]*inv;
        B_s[c2] = Bv*inv;
    }
    __syncthreads();
    {
        const int cl = t >> 4, j = t & 15;
        const int cp = h*16 + cl;
        float m = 0.f;
        #pragma unroll
        for (int hp = 0; hp < 8; ++hp)
            m = fmaf(cwo[cp*8+hp], A_s[cl*8+hp][j], m);
        M_s[cl][j] = m;
        if (j == 0) {
            float cc = cbo[cp];
            #pragma unroll
            for (int hp = 0; hp < 8; ++hp)
                cc = fmaf(cwo[cp*8+hp], B_s[cl*8+hp], cc);
            c_s[cl] = cc;
        }
    }
    __syncthreads();
    {
        const float g  = gamma[0];
        const float gp = gpos[0];
        const int l = t;
        float cv[16];
        #pragma unroll
        for (int cl = 0; cl < 16; ++cl) {
            float a = c_s[cl];
            #pragma unroll
            for (int j = 0; j < 16; ++j)
                a = fmaf(M_s[cl][j], qh[j][l], a);
            cv[cl] = a;
        }
        const ushort_t* p0 = P + ((size_t)b*NL + l)*NC + h*16;
        const ushort_t* p1 = p0 + PHALF;
        const float* qp = qpos + ((size_t)b*NC + h*16)*NL + l;
        #pragma unroll
        for (int q = 0; q < 4; ++q) {
            uint2 u0 = *(const uint2*)(p0 + 4*q);
            uint2 u1 = *(const uint2*)(p1 + 4*q);
            float s0 = bf2f((ushort_t)(u0.x & 0xffffu)) + bf2f((ushort_t)(u1.x & 0xffffu));
            float s1 = bf2f((ushort_t)(u0.x >> 16))     + bf2f((ushort_t)(u1.x >> 16));
            float s2 = bf2f((ushort_t)(u0.y & 0xffffu)) + bf2f((ushort_t)(u1.y & 0xffffu));
            float s3 = bf2f((ushort_t)(u0.y >> 16))     + bf2f((ushort_t)(u1.y >> 16));
            cv[4*q+0] = 0.5f*(qp[(4*q+0)*NL] + gp*(pbo[h*16+4*q+0] + s0) + qh[4*q+0][l] + g*cv[4*q+0]);
            cv[4*q+1] = 0.5f*(qp[(4*q+1)*NL] + gp*(pbo[h*16+4*q+1] + s1) + qh[4*q+1][l] + g*cv[4*q+1]);
            cv[4*q+2] = 0.5f*(qp[(4*q+2)*NL] + gp*(pbo[h*16+4*q+2] + s2) + qh[4*q+2][l] + g*cv[4*q+2]);
            cv[4*q+3] = 0.5f*(qp[(4*q+3)*NL] + gp*(pbo[h*16+4*q+3] + s3) + qh[4*q+3][l] + g*cv[4*q+3]);
        }
        ushort_t* cp = comb + ((size_t)b*NL + l)*NC + h*16;
        uint4 o0, o1;
        o0.x = pack2(cv[0],  cv[1]);   o0.y = pack2(cv[2],  cv[3]);
        o0.z = pack2(cv[4],  cv[5]);   o0.w = pack2(cv[6],  cv[7]);
        o1.x = pack2(cv[8],  cv[9]);   o1.y = pack2(cv[10], cv[11]);
        o1.z = pack2(cv[12], cv[13]);  o1.w = pack2(cv[14], cv[15]);
        *(uint4*)cp       = o0;
        *(uint4*)(cp + 8) = o1;
    }
}

extern "C" void kernel_launch(void* const* d_in, const int* in_sizes, int n_in,
                              void* d_out, int out_size, void* d_ws, size_t ws_size,
                              hipStream_t stream)
{
    const float* qpos = (const float*)d_in[0];
    const float* qcha = (const float*)d_in[1];
    const float* pwq  = (const float*)d_in[2];
    const float* pbq  = (const float*)d_in[3];
    const float* pwk  = (const float*)d_in[4];
    const float* pbk  = (const float*)d_in[5];
    const float* pwv  = (const float*)d_in[6];
    const float* pbv  = (const float*)d_in[7];
    const float* pwo  = (const float*)d_in[8];
    const float* pbo  = (const float*)d_in[9];
    const float* gpos = (const float*)d_in[10];
    const float* cwq  = (const float*)d_in[11];
    const float* cbq  = (const float*)d_in[12];
    const float* cwk  = (const float*)d_in[13];
    const float* cbk  = (const float*)d_in[14];
    const float* cwv  = (const float*)d_in[15];
    const float* cbv  = (const float*)d_in[16];
    const float* cwo  = (const float*)d_in[17];
    const float* cbo  = (const float*)d_in[18];
    const float* gcha = (const float*)d_in[19];
    const float* fw   = (const float*)d_in[20];
    const float* fb   = (const float*)d_in[21];
    float* outp = (float*)d_out;

    char* ws = (char*)d_ws;
    ushort_t* att  = (ushort_t*)ws;                       // 33,554,432 B (NHWC bf16)
    ushort_t* comb = (ushort_t*)ws;                       //  8,388,608 B (bf16 NHWC, overlays att)
    ushort_t* P    = (ushort_t*)(ws + 33554432);          // 16,777,216 B (2 bf16 partial halves)
    ushort_t* xbf  = (ushort_t*)(ws + 33554432);          //  8,388,608 B (overlays P; dead before conv_ci)
    short*    wp1  = (short*)(ws + 50331648);             //  1,179,648 B
    short*    wp2  = (short*)(ws + 51511296);             //    294,912 B
    short*    wpq  = (short*)(ws + 51806208);             //     32,768 B
    short*    wpk  = (short*)(ws + 51838976);             //     32,768 B
    short*    wpv  = (short*)(ws + 51871744);             //    131,072 B

    k_wpack_conv<<<dim3(2880), 256, 0, stream>>>(pwo, fw, wp1, wp2);
    k_wpack_qkv3<<<dim3(384),  256, 0, stream>>>(pwq, pwk, pwv, wpq, wpk, wpv);

    k_xpose<<<dim3(2, NB), 256, 0, stream>>>(qpos, xbf);
    k_pos_mfma<<<dim3(NH, NB), 512, 0, stream>>>(xbf, wpq, wpk, wpv,
                                                 pbq, pbk, pbv, att);
    k_conv_ci<<<dim3(4, NB), 256, 0, stream>>>(att, wp1, P);
    k_cha<<<dim3(NH, NB), 256, 0, stream>>>(qcha, cwq, cbq, cwk, cbk, cwv, cbv,
                                            cwo, cbo, gcha,
                                            P, qpos, pbo, gpos, comb);
    k_conv_co<<<dim3(4, NB), 256, 0, stream>>>(comb, wp2, fb, outp);
}

// Round 19
// 160.593 us; speedup vs baseline: 1.1403x; 1.0090x over previous
//
#include <hip/hip_runtime.h>
#include <cstdint>
#include <cstddef>

typedef unsigned short ushort_t;
typedef unsigned int uint_t;
typedef __attribute__((ext_vector_type(8))) short bf16x8;
typedef __attribute__((ext_vector_type(4))) float f32x4;

#define NB 128
#define NC 128
#define NL 256
#define NH 8
#define HD 16
#define HDV 64
#define NEV 512
#define PHALF 4194304   // elements per conv1 partial half (128*256*128)

__device__ __forceinline__ ushort_t f2bf(float f) {
    uint_t u = __float_as_uint(f);
    u += 0x7fffu + ((u >> 16) & 1u);
    return (ushort_t)(u >> 16);
}
__device__ __forceinline__ float bf2f(ushort_t s) {
    return __uint_as_float(((uint_t)s) << 16);
}
// single-instruction packed f32->bf16 (RNE), lo in low 16 bits
__device__ __forceinline__ uint_t pack2(float lo, float hi) {
    uint_t r;
    asm("v_cvt_pk_bf16_f32 %0, %1, %2" : "=v"(r) : "v"(lo), "v"(hi));
    return r;
}

// ---------------- pack helpers (device) ----------------
template<int CIN, int GRP>
__device__ __forceinline__ void wpack_one(int idx, const float* __restrict__ w,
                                          short* __restrict__ wp) {
    constexpr int LG = (GRP == 4) ? 2 : 1;
    int j    = idx & 7;
    int r    = (idx >> 3) & (GRP - 1);
    int lane = (idx >> (3 + LG)) & 63;
    int gidx = (idx >> (9 + LG)) & ((8 / GRP) - 1);
    int tc   = idx >> 12;
    int tap  = tc % 9;
    int ch   = tc / 9;
    int co   = (gidx * GRP + r) * 16 + (lane & 15);
    int ci   = ch * 32 + (lane >> 4) * 8 + j;
    wp[idx] = (short)f2bf(w[((size_t)co * CIN + ci) * 9 + tap]);
}

// ---------------- K0: merged conv-weight pack (conv1 GRP=4, conv2 GRP=2)
__global__ __launch_bounds__(256) void k_wpack_conv(const float* __restrict__ pwo,
                                                    const float* __restrict__ fw,
                                                    short* __restrict__ wp1,
                                                    short* __restrict__ wp2) {
    const int bid = blockIdx.x;
    if (bid < 2304) {
        int idx = bid * 256 + threadIdx.x;          // NEV*1152 = 589824 exactly
        wpack_one<NEV, 4>(idx, pwo, wp1);
    } else {
        int idx = (bid - 2304) * 256 + threadIdx.x; // NC*1152 = 147456 exactly
        wpack_one<NC, 2>(idx, fw, wp2);
    }
}

// ---------------- K0b: merged projection-weight pack (q, k, v)
__device__ __forceinline__ void qkvpack_one(int idx, const float* __restrict__ w,
                                            short* __restrict__ wp) {
    int j    = idx & 7;
    int lane = (idx >> 3) & 63;
    int ch   = (idx >> 9) & 3;
    int rt   = idx >> 11;
    int n = lane & 15, g = lane >> 4;
    wp[idx] = (short)f2bf(w[(size_t)(rt*16 + n)*128 + ch*32 + g*8 + j]);
}
__global__ __launch_bounds__(256) void k_wpack_qkv3(const float* __restrict__ pwq,
                                                    const float* __restrict__ pwk,
                                                    const float* __restrict__ pwv,
                                                    short* __restrict__ wpq,
                                                    short* __restrict__ wpk,
                                                    short* __restrict__ wpv) {
    const int bid = blockIdx.x;
    if (bid < 64) {
        qkvpack_one(bid * 256 + threadIdx.x, pwq, wpq);          // 128*128 = 16384
    } else if (bid < 128) {
        qkvpack_one((bid - 64) * 256 + threadIdx.x, pwk, wpk);
    } else {
        qkvpack_one((bid - 128) * 256 + threadIdx.x, pwv, wpv);  // 512*128 = 65536
    }
}

// ---------------- K0c: transpose X (NCHW f32) -> xbf (NHWC bf16), once.
__global__ __launch_bounds__(256) void k_xpose(const float* __restrict__ x,
                                               ushort_t* __restrict__ xbf) {
    const int half = blockIdx.x, b = blockIdx.y, t = threadIdx.x;
    const float* src = x + (size_t)b*NC*NL + (size_t)half*64*NL + t;
    uint_t* dst = (uint_t*)(xbf + ((size_t)b*NL + t)*NC + half*64);
    #pragma unroll
    for (int k8 = 0; k8 < 8; ++k8) {
        uint4 u;
        u.x = pack2(src[(k8*8+0)*NL], src[(k8*8+1)*NL]);
        u.y = pack2(src[(k8*8+2)*NL], src[(k8*8+3)*NL]);
        u.z = pack2(src[(k8*8+4)*NL], src[(k8*8+5)*NL]);
        u.w = pack2(src[(k8*8+6)*NL], src[(k8*8+7)*NL]);
        *(uint4*)(dst + k8*4) = u;
    }
}

// ---------------- K1: full-MFMA position attention. Block = (h, b), 8 waves x 32 q.
__global__ __launch_bounds__(512, 4) void k_pos_mfma(
    const ushort_t* __restrict__ xbf,
    const short* __restrict__ wpq, const short* __restrict__ wpk,
    const short* __restrict__ wpv,
    const float* __restrict__ bq, const float* __restrict__ bk,
    const float* __restrict__ bv,
    ushort_t* __restrict__ att)
{
    const int h = blockIdx.x, b = blockIdx.y;
    const int t = threadIdx.x;
    const int lane = t & 63, w = t >> 6;
    const int n = lane & 15, g = lane >> 4;

    __shared__ __align__(16) short lds[26112];   // 52,224 B

    const f32x4 z4 = {0.f, 0.f, 0.f, 0.f};
    f32x4 qacc[2], kacc[2], vacc[4][2];
    #pragma unroll
    for (int ct = 0; ct < 2; ++ct) { qacc[ct] = z4; kacc[ct] = z4; }
    #pragma unroll
    for (int vt = 0; vt < 4; ++vt)
        #pragma unroll
        for (int ct = 0; ct < 2; ++ct) vacc[vt][ct] = z4;

    const ushort_t* xr = xbf + ((size_t)(b*NL + w*32 + n))*NC;

    #pragma unroll 2
    for (int ch = 0; ch < 4; ++ch) {
        bf16x8 xb[2];
        #pragma unroll
        for (int ct = 0; ct < 2; ++ct)
            xb[ct] = *(const bf16x8*)(xr + ct*16*NC + ch*32 + g*8);
        const size_t fo = ((size_t)((h*4 + ch)*64) + lane) * 8;
        bf16x8 aq = *(const bf16x8*)(wpq + fo);
        bf16x8 ak = *(const bf16x8*)(wpk + fo);
        __builtin_amdgcn_s_setprio(1);
        #pragma unroll
        for (int ct = 0; ct < 2; ++ct)
            qacc[ct] = __builtin_amdgcn_mfma_f32_16x16x32_bf16(aq, xb[ct], qacc[ct], 0, 0, 0);
        #pragma unroll
        for (int ct = 0; ct < 2; ++ct)
            kacc[ct] = __builtin_amdgcn_mfma_f32_16x16x32_bf16(ak, xb[ct], kacc[ct], 0, 0, 0);
        __builtin_amdgcn_s_setprio(0);
        #pragma unroll
        for (int vt = 0; vt < 4; ++vt) {
            bf16x8 av = *(const bf16x8*)(wpv + ((size_t)((((h*4 + vt)*4) + ch)*64) + lane) * 8);
            __builtin_amdgcn_s_setprio(1);
            #pragma unroll
            for (int ct = 0; ct < 2; ++ct)   // SWAPPED: D[l][dv]
                vacc[vt][ct] = __builtin_amdgcn_mfma_f32_16x16x32_bf16(xb[ct], av, vacc[vt][ct], 0, 0, 0);
            __builtin_amdgcn_s_setprio(0);
        }
    }

    uint_t qu01[2], qu23[2];
    {
        float bqv[4], bkv[4];
        #pragma unroll
        for (int r = 0; r < 4; ++r) {
            bqv[r] = bq[h*16 + g*4 + r];
            bkv[r] = bk[h*16 + g*4 + r];
        }
        #pragma unroll
        for (int ct = 0; ct < 2; ++ct) {
            qu01[ct] = pack2(qacc[ct][0] + bqv[0], qacc[ct][1] + bqv[1]);
            qu23[ct] = pack2(qacc[ct][2] + bqv[2], qacc[ct][3] + bqv[3]);
            uint2 kp;
            kp.x = pack2(kacc[ct][0] + bkv[0], kacc[ct][1] + bkv[1]);
            kp.y = pack2(kacc[ct][2] + bkv[2], kacc[ct][3] + bkv[3]);
            *(uint2*)&lds[(w*32 + ct*16 + n)*16 + g*4] = kp;
        }
        #pragma unroll
        for (int vt = 0; vt < 4; ++vt) {
            const float bvv = bv[h*64 + vt*16 + n];
            #pragma unroll
            for (int ct = 0; ct < 2; ++ct) {
                uint2 vp;
                vp.x = pack2(vacc[vt][ct][0] + bvv, vacc[vt][ct][1] + bvv);
                vp.y = pack2(vacc[vt][ct][2] + bvv, vacc[vt][ct][3] + bvv);
                *(uint2*)&lds[9216 + (vt*16 + n)*264 + w*32 + ct*16 + g*4] = vp;
            }
        }
    }
    __syncthreads();

    const int a0 = (n + 32*(g & 1)) * 4;
    #pragma unroll 1
    for (int qt = 0; qt < 2; ++qt) {
        union { uint_t u[4]; bf16x8 v; } qfu;
        qfu.u[0] = (uint_t)__builtin_amdgcn_ds_bpermute(a0,      (int)qu01[qt]);
        qfu.u[1] = (uint_t)__builtin_amdgcn_ds_bpermute(a0,      (int)qu23[qt]);
        qfu.u[2] = (uint_t)__builtin_amdgcn_ds_bpermute(a0 + 64, (int)qu01[qt]);
        qfu.u[3] = (uint_t)__builtin_amdgcn_ds_bpermute(a0 + 64, (int)qu23[qt]);
        if (g >= 2) { qfu.u[0] = 0; qfu.u[1] = 0; qfu.u[2] = 0; qfu.u[3] = 0; }
        bf16x8 qf = qfu.v;

        f32x4 s[16];
        __builtin_amdgcn_s_setprio(1);
        #pragma unroll
        for (int kt = 0; kt < 16; ++kt) {
            bf16x8 kf = (bf16x8){0,0,0,0,0,0,0,0};
            if (g < 2) kf = *(const bf16x8*)&lds[(kt*16 + n)*16 + g*8];
            s[kt] = __builtin_amdgcn_mfma_f32_16x16x32_bf16(kf, qf, z4, 0, 0, 0);
        }
        __builtin_amdgcn_s_setprio(0);
        float d0 = 0.f, d1 = 0.f, d2 = 0.f, d3 = 0.f;
        #pragma unroll
        for (int kt = 0; kt < 16; ++kt) {
            float e0 = exp2f(s[kt][0] * 0.36067376022224085f);
            float e1 = exp2f(s[kt][1] * 0.36067376022224085f);
            float e2 = exp2f(s[kt][2] * 0.36067376022224085f);
            float e3 = exp2f(s[kt][3] * 0.36067376022224085f);
            s[kt][0] = e0; s[kt][1] = e1; s[kt][2] = e2; s[kt][3] = e3;
            d0 += e0; d1 += e1; d2 += e2; d3 += e3;
        }
        float den = (d0 + d1) + (d2 + d3);
        den += __shfl_xor(den, 16);
        den += __shfl_xor(den, 32);
        const float inv = 1.f / den;

        f32x4 oacc[4] = {z4, z4, z4, z4};
        #pragma unroll
        for (int c2 = 0; c2 < 8; ++c2) {
            #pragma unroll
            for (int u = 0; u < 2; ++u) {
                const int kt = 2*c2 + u;
                uint2 pp;
                pp.x = pack2(s[kt][0], s[kt][1]);
                pp.y = pack2(s[kt][2], s[kt][3]);
                *(uint2*)&lds[4096 + w*640 + n*40 + u*16 + g*4] = pp;
            }
            bf16x8 pf = *(const bf16x8*)&lds[4096 + w*640 + n*40 + g*8];
            __builtin_amdgcn_s_setprio(1);
            #pragma unroll
            for (int vt = 0; vt < 4; ++vt) {
                bf16x8 av = *(const bf16x8*)&lds[9216 + (vt*16 + n)*264 + c2*32 + g*8];
                oacc[vt] = __builtin_amdgcn_mfma_f32_16x16x32_bf16(av, pf, oacc[vt], 0, 0, 0);
            }
            __builtin_amdgcn_s_setprio(0);
        }
        ushort_t* ap = att + (((size_t)b*NL + (w*32 + qt*16 + n))*NEV + h*HDV + g*4);
        #pragma unroll
        for (int vt = 0; vt < 4; ++vt) {
            uint2 op;
            op.x = pack2(oacc[vt][0]*inv, oacc[vt][1]*inv);
            op.y = pack2(oacc[vt][2]*inv, oacc[vt][3]*inv);
            *(uint2*)(ap + vt*16) = op;
        }
    }
}

// ---------------- K2: conv1 (3x3, 512->128) ci+l-split, global_load_lds DMA staging.
// grid (4, NB): blockIdx.x = kc*2 + lh. Block = 128co x 128l x 256ci,
// 4 waves (2co x 2l), wave tile 64co x 64l.
// LDS: halo-free image [10 yp][4 gg][16 x][8] bf16, double-buffered (20 KB).
__global__ __launch_bounds__(256, 2) void k_conv_ci(
    const ushort_t* __restrict__ att, const short* __restrict__ wp,
    ushort_t* __restrict__ P)
{
    const int kc = blockIdx.x >> 1, lh = blockIdx.x & 1, b = blockIdx.y;
    const int t = threadIdx.x;
    const int lane = t & 63, w = t >> 6;
    const int wr = w >> 1, wc = w & 1;
    const int n = lane & 15, gl = lane >> 4;
    const int y0 = lh * 8;

    __shared__ __align__(16) short ims[2][5120];   // 2 x 10 KB

    {   // zero both buffers once (oob rows never DMA'd -> stay zero)
        bf16x8 z = {0,0,0,0,0,0,0,0};
        bf16x8* p = (bf16x8*)&ims[0][0];
        for (int i = t; i < 1280; i += 256) p[i] = z;
    }

    f32x4 acc[4][4];
    #pragma unroll
    for (int i = 0; i < 4; ++i)
        #pragma unroll
        for (int j = 0; j < 4; ++j) acc[i][j] = (f32x4){0.f,0.f,0.f,0.f};

    const ushort_t* abase = att + (size_t)b*NL*NEV + kc*256 +
                            (size_t)(lane & 15)*NEV + (lane >> 4)*8;

    auto issue_dma = [&](int ch, int bsel) {
        short* dst0 = &ims[bsel][0];
        #pragma unroll
        for (int rr = 0; rr < 3; ++rr) {
            const int yp = w + rr*4;
            if (yp < 10) {
                const int y = y0 - 1 + yp;
                if (y >= 0 && y < 16) {
                    const ushort_t* src = abase + (size_t)(y*16)*NEV + ch*32;
                    __builtin_amdgcn_global_load_lds(
                        (const __attribute__((address_space(1))) void*)src,
                        (__attribute__((address_space(3))) void*)(dst0 + yp*512),
                        16, 0, 0);
                }
            }
        }
    };

    const short* wpl = wp + (size_t)lane * 32;
    auto Aaddr = [&](int ch16, int tap) {
        return (const bf16x8*)(wpl + ((size_t)((ch16*9 + tap)*2 + wr)) * 2048);
    };
    auto bload = [&](const short* buf, int r, int xc) -> bf16x8 {
        return *(const bf16x8*)&buf[(r*64 + gl*16 + xc)*8];
    };

    bf16x8 Abuf[3][4];
    bf16x8 Bc[4], Bn[4];
    const bf16x8 zf = {0,0,0,0,0,0,0,0};
    #pragma unroll
    for (int i = 0; i < 4; ++i) { Bc[i] = zf; Bn[i] = zf; }

    __syncthreads();              // zero-init visible to all
    issue_dma(0, 0);              // prefetch chunk 0

    #pragma unroll 1
    for (int ch = 0; ch < 8; ++ch) {
        const int ch16 = kc*8 + ch;
        __syncthreads();          // DMA(ch) landed; prior compute done
        const short* buf = &ims[ch & 1][0];
        #pragma unroll
        for (int p = 0; p < 3; ++p) {
            const bf16x8* ap = Aaddr(ch16, p);
            #pragma unroll
            for (int rt = 0; rt < 4; ++rt) Abuf[p][rt] = ap[rt];
        }
        {
            const int xc = (n == 0) ? 0 : n - 1;
            #pragma unroll
            for (int ct = 0; ct < 4; ++ct)
                Bc[ct] = bload(buf, wc*4 + ct, xc);
            if (n == 0) {
                #pragma unroll
                for (int ct = 0; ct < 4; ++ct) Bc[ct] = zf;
            }
        }

        #pragma unroll
        for (int tap = 0; tap < 9; ++tap) {
            if (tap < 8) {
                const int dy = (tap + 1) / 3, dx = (tap + 1) % 3;
                const int xx = n + dx - 1;
                const int xc = (xx < 0) ? 0 : (xx > 15 ? 15 : xx);
                #pragma unroll
                for (int ct = 0; ct < 4; ++ct)
                    Bn[ct] = bload(buf, wc*4 + ct + dy, xc);
                if (dx == 0) {
                    if (n == 0) {
                        #pragma unroll
                        for (int ct = 0; ct < 4; ++ct) Bn[ct] = zf;
                    }
                } else if (dx == 2) {
                    if (n == 15) {
                        #pragma unroll
                        for (int ct = 0; ct < 4; ++ct) Bn[ct] = zf;
                    }
                }
            }
            __builtin_amdgcn_s_setprio(1);   // T5: favor MFMA-phase waves
            #pragma unroll
            for (int rt = 0; rt < 4; ++rt)
                #pragma unroll
                for (int ct = 0; ct < 4; ++ct)
                    acc[rt][ct] = __builtin_amdgcn_mfma_f32_16x16x32_bf16(
                        Abuf[tap % 3][rt], Bc[ct], acc[rt][ct], 0, 0, 0);
            __builtin_amdgcn_s_setprio(0);
            if (tap + 3 < 9) {
                const bf16x8* ap = Aaddr(ch16, tap + 3);
                #pragma unroll
                for (int rt = 0; rt < 4; ++rt) Abuf[tap % 3][rt] = ap[rt];
            }
            if (tap == 5 && ch < 7)
                issue_dma(ch + 1, (ch + 1) & 1);   // rides under taps 6-8 + barrier
            #pragma unroll
            for (int i = 0; i < 4; ++i)
                if (tap < 8) Bc[i] = Bn[i];
        }
    }

    ushort_t* Pb = P + (size_t)kc * PHALF + (size_t)b * NL * NC;
    #pragma unroll
    for (int rt = 0; rt < 4; ++rt) {
        const int co0 = wr*64 + rt*16 + gl*4;
        #pragma unroll
        for (int ct = 0; ct < 4; ++ct) {
            const int l = lh*128 + wc*64 + ct*16 + n;
            uint2 u;
            u.x = pack2(acc[rt][ct][0], acc[rt][ct][1]);
            u.y = pack2(acc[rt][ct][2], acc[rt][ct][3]);
            *(uint2*)(Pb + (size_t)l*NC + co0) = u;
        }
    }
}

// ---------------- K4: conv2 (3x3, 128->128) co+l-split, T14 + depth-3 A pipeline.
__global__ __launch_bounds__(256, 2) void k_conv_co(
    const ushort_t* __restrict__ comb, const short* __restrict__ wp,
    const float* __restrict__ bias, float* __restrict__ out)
{
    const int kc = blockIdx.x >> 1, lh = blockIdx.x & 1, b = blockIdx.y;
    const int t = threadIdx.x;
    const int lane = t & 63, w = t >> 6;
    const int wr = w >> 1, wc = w & 1;
    const int n = lane & 15, gl = lane >> 4;
    const int y0 = lh * 8;

    __shared__ __align__(16) short ims[2][5760];

    {
        bf16x8 z = {0,0,0,0,0,0,0,0};
        bf16x8* p = (bf16x8*)&ims[0][0];
        for (int i = t; i < 1440; i += 256) p[i] = z;
    }

    f32x4 acc[2][4];
    #pragma unroll
    for (int i = 0; i < 2; ++i)
        #pragma unroll
        for (int j = 0; j < 4; ++j) acc[i][j] = (f32x4){0.f,0.f,0.f,0.f};

    const int gg1 = t & 3,        xx1 = (t >> 2) & 15,        yp1 = t >> 6;
    const int id2 = t + 256;
    const int gg2 = id2 & 3,      xx2 = (id2 >> 2) & 15,      yp2 = id2 >> 6;
    const int id3 = t + 512;
    const int gg3 = id3 & 3,      xx3 = (id3 >> 2) & 15,      yp3 = id3 >> 6;
    const bool has3 = (t < 128);
    const int y1 = y0 - 1 + yp1, y2 = y0 - 1 + yp2, y3 = y0 - 1 + yp3;
    const bool ok1 = (y1 >= 0) && (y1 < 16);
    const bool ok2 = (y2 >= 0) && (y2 < 16);
    const bool ok3 = has3 && (y3 >= 0) && (y3 < 16);
    const ushort_t* s1 = comb + ((size_t)(b*NL + y1*16 + xx1))*NC + gg1*8;
    const ushort_t* s2 = comb + ((size_t)(b*NL + y2*16 + xx2))*NC + gg2*8;
    const ushort_t* s3 = comb + ((size_t)(b*NL + y3*16 + xx3))*NC + gg3*8;
    const int slot1 = ((yp1*4 + gg1)*18 + xx1 + 1) * 8;
    const int slot2 = ((yp2*4 + gg2)*18 + xx2 + 1) * 8;
    const int slot3 = ((yp3*4 + gg3)*18 + xx3 + 1) * 8;

    bf16x8 v1 = {0,0,0,0,0,0,0,0}, v2 = v1, v3 = v1;
    if (ok1) v1 = *(const bf16x8*)s1;
    if (ok2) v2 = *(const bf16x8*)s2;
    if (ok3) v3 = *(const bf16x8*)s3;

    const short* wpl = wp + (size_t)lane * 16;
    auto Aaddr = [&](int ch, int tap) {
        return (const bf16x8*)(wpl + ((size_t)((ch*9 + tap)*4 + kc*2 + wr)) * 1024);
    };

    bf16x8 Abuf[3][2];
    bf16x8 Bc[4], Bn[4];
    #pragma unroll
    for (int i = 0; i < 4; ++i) { Bc[i] = (bf16x8){0,0,0,0,0,0,0,0}; Bn[i] = Bc[i]; }

    __syncthreads();

    #pragma unroll 1
    for (int ch = 0; ch < 4; ++ch) {
        short* buf = &ims[ch & 1][0];
        *(bf16x8*)&buf[slot1] = v1;
        *(bf16x8*)&buf[slot2] = v2;
        if (has3) *(bf16x8*)&buf[slot3] = v3;
        __syncthreads();
        if (ch < 3) {                        // T14: issue after barrier
            if (ok1) v1 = *(const bf16x8*)(s1 + (ch + 1) * 32);
            if (ok2) v2 = *(const bf16x8*)(s2 + (ch + 1) * 32);
            if (ok3) v3 = *(const bf16x8*)(s3 + (ch + 1) * 32);
        }
        #pragma unroll
        for (int p = 0; p < 3; ++p) {
            const bf16x8* ap = Aaddr(ch, p);
            #pragma unroll
            for (int rt = 0; rt < 2; ++rt) Abuf[p][rt] = ap[rt];
        }
        #pragma unroll
        for (int ct = 0; ct < 4; ++ct)
            Bc[ct] = *(const bf16x8*)&buf[(((wc*4 + ct)*4 + gl)*18 + n) * 8];

        #pragma unroll
        for (int tap = 0; tap < 9; ++tap) {
            if (tap < 8) {
                const int dy = (tap + 1) / 3, dx = (tap + 1) % 3;
                #pragma unroll
                for (int ct = 0; ct < 4; ++ct)
                    Bn[ct] = *(const bf16x8*)&buf[(((wc*4 + ct + dy)*4 + gl)*18 + n + dx) * 8];
            }
            __builtin_amdgcn_s_setprio(1);   // T5
            #pragma unroll
            for (int rt = 0; rt < 2; ++rt)
                #pragma unroll
                for (int ct = 0; ct < 4; ++ct)
                    acc[rt][ct] = __builtin_amdgcn_mfma_f32_16x16x32_bf16(
                        Abuf[tap % 3][rt], Bc[ct], acc[rt][ct], 0, 0, 0);
            __builtin_amdgcn_s_setprio(0);
            if (tap + 3 < 9) {
                const bf16x8* ap = Aaddr(ch, tap + 3);
                #pragma unroll
                for (int rt = 0; rt < 2; ++rt) Abuf[tap % 3][rt] = ap[rt];
            }
            #pragma unroll
            for (int i = 0; i < 4; ++i)
                if (tap < 8) Bc[i] = Bn[i];
        }
    }

    #pragma unroll
    for (int rt = 0; rt < 2; ++rt) {
        const int co0 = kc*64 + wr*32 + rt*16 + gl*4;
        const float c0 = bias[co0+0], c1 = bias[co0+1],
                    c2 = bias[co0+2], c3 = bias[co0+3];
        #pragma unroll
        for (int ct = 0; ct < 4; ++ct) {
            const int l = lh*128 + wc*64 + ct*16 + n;
            f32x4 a = acc[rt][ct];
            out[((size_t)b*NC + co0+0)*NL + l] = c0 + a[0];
            out[((size_t)b*NC + co0+1)*NL + l] = c1 + a[1];
            out[((size_t)b*NC + co0+2)*NL + l] = c2 + a[2];
            out[((size_t)b*NC + co0+3)*NL + l] = c3 + a[3];
        }
    }
}

// ---------------- K3: channel attention + fold conv1 partials + pos residual + fusion.
#define NLP 260
__global__ __launch_bounds__(256) void k_cha(
    const float* __restrict__ xc,
    const float* __restrict__ cwq, const float* __restrict__ cbq,
    const float* __restrict__ cwk, const float* __restrict__ cbk,
    const float* __restrict__ cwv, const float* __restrict__ cbv,
    const float* __restrict__ cwo, const float* __restrict__ cbo,
    const float* __restrict__ gamma,
    const ushort_t* __restrict__ P, const float* __restrict__ qpos,
    const float* __restrict__ pbo, const float* __restrict__ gpos,
    ushort_t* __restrict__ comb)
{
    const int h = blockIdx.x, b = blockIdx.y, t = threadIdx.x;
    __shared__ float qh[16][NLP];
    __shared__ float G_s[16][17];
    __shared__ float S_s[16];
    __shared__ float wq_s[128], bq_s[128], wk_s[128], bk_s[128], wv_s[128], bv_s[128];
    __shared__ float A_s[128][17];
    __shared__ float B_s[128];
    __shared__ float M_s[16][17];
    __shared__ float c_s[16];

    #pragma unroll
    for (int j = 0; j < 16; ++j)
        qh[j][t] = xc[((size_t)b*NC + h*16 + j)*NL + t];
    if (t < 128) {
        const int k = h*128 + t;
        wq_s[t] = cwq[k]; bq_s[t] = cbq[k];
        wk_s[t] = cwk[k]; bk_s[t] = cbk[k];
        wv_s[t] = cwv[k]; bv_s[t] = cbv[k];
    }
    __syncthreads();
    {
        const int i = t >> 4, j = t & 15;
        const float4* qi = (const float4*)qh[i];
        const float4* qj = (const float4*)qh[j];
        float gg = 0.f;
        for (int l4 = 0; l4 < NL/4; ++l4) {
            float4 a = qi[l4], c = qj[l4];
            gg = fmaf(a.x,c.x,fmaf(a.y,c.y,fmaf(a.z,c.z,fmaf(a.w,c.w,gg))));
        }
        G_s[i][j] = gg;
    }
    if (t < 16) {
        const float4* qi = (const float4*)qh[t];
        float s = 0.f;
        for (int l4 = 0; l4 < NL/4; ++l4) { float4 a = qi[l4]; s += a.x + a.y + a.z + a.w; }
        S_s[t] = s;
    }
    __syncthreads();
    if (t < 128) {
        const int c2 = t, cg = c2 >> 3;
        const float wqc = wq_s[c2], bqc = bq_s[c2];
        float Pv[16];
        #pragma unroll
        for (int j = 0; j < 16; ++j) Pv[j] = wqc*G_s[cg][j] + bqc*S_s[j];
        const float Qc = wqc*S_s[cg] + bqc*256.0f;
        float mx = -3.0e38f;
        #pragma unroll
        for (int dg = 0; dg < 16; ++dg) {
            #pragma unroll
            for (int dj = 0; dj < 8; ++dj) {
                const int d = dg*8 + dj;
                float s = wk_s[d]*Pv[dg] + bk_s[d]*Qc;
                mx = fmaxf(mx, s);
            }
        }
        float A[16];
        #pragma unroll
        for (int j = 0; j < 16; ++j) A[j] = 0.f;
        float Bv = 0.f, den = 0.f;
        #pragma unroll
        for (int dg = 0; dg < 16; ++dg) {
            #pragma unroll
            for (int dj = 0; dj < 8; ++dj) {
                const int d = dg*8 + dj;
                float s = wk_s[d]*Pv[dg] + bk_s[d]*Qc;
                float e = __expf((s - mx) * 0.0625f);
                den += e;
                A[dg] = fmaf(e, wv_s[d], A[dg]);
                Bv = fmaf(e, bv_s[d], Bv);
            }
        }
        const float inv = 1.f / den;
        #pragma unroll
        for (int j = 0; j < 16; ++j) A_s[c2][j] = A[j]*inv;
        B_s[c2] = Bv*inv;
    }
    __syncthreads();
    {
        const int cl = t >> 4, j = t & 15;
        const int cp = h*16 + cl;
        float m = 0.f;
        #pragma unroll
        for (int hp = 0; hp < 8; ++hp)
            m = fmaf(cwo[cp*8+hp], A_s[cl*8+hp][j], m);
        M_s[cl][j] = m;
        if (j == 0) {
            float cc = cbo[cp];
            #pragma unroll
            for (int hp = 0; hp < 8; ++hp)
                cc = fmaf(cwo[cp*8+hp], B_s[cl*8+hp], cc);
            c_s[cl] = cc;
        }
    }
    __syncthreads();
    {
        const float g  = gamma[0];
        const float gp = gpos[0];
        const int l = t;
        float cv[16];
        #pragma unroll
        for (int cl = 0; cl < 16; ++cl) {
            float a = c_s[cl];
            #pragma unroll
            for (int j = 0; j < 16; ++j)
                a = fmaf(M_s[cl][j], qh[j][l], a);
            cv[cl] = a;
        }
        const ushort_t* p0 = P + ((size_t)b*NL + l)*NC + h*16;
        const ushort_t* p1 = p0 + PHALF;
        const float* qp = qpos + ((size_t)b*NC + h*16)*NL + l;
        #pragma unroll
        for (int q = 0; q < 4; ++q) {
            uint2 u0 = *(const uint2*)(p0 + 4*q);
            uint2 u1 = *(const uint2*)(p1 + 4*q);
            float s0 = bf2f((ushort_t)(u0.x & 0xffffu)) + bf2f((ushort_t)(u1.x & 0xffffu));
            float s1 = bf2f((ushort_t)(u0.x >> 16))     + bf2f((ushort_t)(u1.x >> 16));
            float s2 = bf2f((ushort_t)(u0.y & 0xffffu)) + bf2f((ushort_t)(u1.y & 0xffffu));
            float s3 = bf2f((ushort_t)(u0.y >> 16))     + bf2f((ushort_t)(u1.y >> 16));
            cv[4*q+0] = 0.5f*(qp[(4*q+0)*NL] + gp*(pbo[h*16+4*q+0] + s0) + qh[4*q+0][l] + g*cv[4*q+0]);
            cv[4*q+1] = 0.5f*(qp[(4*q+1)*NL] + gp*(pbo[h*16+4*q+1] + s1) + qh[4*q+1][l] + g*cv[4*q+1]);
            cv[4*q+2] = 0.5f*(qp[(4*q+2)*NL] + gp*(pbo[h*16+4*q+2] + s2) + qh[4*q+2][l] + g*cv[4*q+2]);
            cv[4*q+3] = 0.5f*(qp[(4*q+3)*NL] + gp*(pbo[h*16+4*q+3] + s3) + qh[4*q+3][l] + g*cv[4*q+3]);
        }
        ushort_t* cp = comb + ((size_t)b*NL + l)*NC + h*16;
        uint4 o0, o1;
        o0.x = pack2(cv[0],  cv[1]);   o0.y = pack2(cv[2],  cv[3]);
        o0.z = pack2(cv[4],  cv[5]);   o0.w = pack2(cv[6],  cv[7]);
        o1.x = pack2(cv[8],  cv[9]);   o1.y = pack2(cv[10], cv[11]);
        o1.z = pack2(cv[12], cv[13]);  o1.w = pack2(cv[14], cv[15]);
        *(uint4*)cp       = o0;
        *(uint4*)(cp + 8) = o1;
    }
}

extern "C" void kernel_launch(void* const* d_in, const int* in_sizes, int n_in,
                              void* d_out, int out_size, void* d_ws, size_t ws_size,
                              hipStream_t stream)
{
    const float* qpos = (const float*)d_in[0];
    const float* qcha = (const float*)d_in[1];
    const float* pwq  = (const float*)d_in[2];
    const float* pbq  = (const float*)d_in[3];
    const float* pwk  = (const float*)d_in[4];
    const float* pbk  = (const float*)d_in[5];
    const float* pwv  = (const float*)d_in[6];
    const float* pbv  = (const float*)d_in[7];
    const float* pwo  = (const float*)d_in[8];
    const float* pbo  = (const float*)d_in[9];
    const float* gpos = (const float*)d_in[10];
    const float* cwq  = (const float*)d_in[11];
    const float* cbq  = (const float*)d_in[12];
    const float* cwk  = (const float*)d_in[13];
    const float* cbk  = (const float*)d_in[14];
    const float* cwv  = (const float*)d_in[15];
    const float* cbv  = (const float*)d_in[16];
    const float* cwo  = (const float*)d_in[17];
    const float* cbo  = (const float*)d_in[18];
    const float* gcha = (const float*)d_in[19];
    const float* fw   = (const float*)d_in[20];
    const float* fb   = (const float*)d_in[21];
    float* outp = (float*)d_out;

    char* ws = (char*)d_ws;
    ushort_t* att  = (ushort_t*)ws;                       // 33,554,432 B (NHWC bf16)
    ushort_t* comb = (ushort_t*)ws;                       //  8,388,608 B (bf16 NHWC, overlays att)
    ushort_t* P    = (ushort_t*)(ws + 33554432);          // 16,777,216 B (2 bf16 partial halves)
    ushort_t* xbf  = (ushort_t*)(ws + 33554432);          //  8,388,608 B (overlays P; dead before conv_ci)
    short*    wp1  = (short*)(ws + 50331648);             //  1,179,648 B
    short*    wp2  = (short*)(ws + 51511296);             //    294,912 B
    short*    wpq  = (short*)(ws + 51806208);             //     32,768 B
    short*    wpk  = (short*)(ws + 51838976);             //     32,768 B
    short*    wpv  = (short*)(ws + 51871744);             //    131,072 B

    k_wpack_conv<<<dim3(2880), 256, 0, stream>>>(pwo, fw, wp1, wp2);
    k_wpack_qkv3<<<dim3(384),  256, 0, stream>>>(pwq, pwk, pwv, wpq, wpk, wpv);

    k_xpose<<<dim3(2, NB), 256, 0, stream>>>(qpos, xbf);
    k_pos_mfma<<<dim3(NH, NB), 512, 0, stream>>>(xbf, wpq, wpk, wpv,
                                                 pbq, pbk, pbv, att);
    k_conv_ci<<<dim3(4, NB), 256, 0, stream>>>(att, wp1, P);
    k_cha<<<dim3(NH, NB), 256, 0, stream>>>(qcha, cwq, cbq, cwk, cbk, cwv, cbv,
                                            cwo, cbo, gcha,
                                            P, qpos, pbo, gpos, comb);
    k_conv_co<<<dim3(4, NB), 256, 0, stream>>>(comb, wp2, fb, outp);
}